// Round 16
// baseline (218.963 us; speedup 1.0000x reference)
//
#include <hip/hip_runtime.h>
#include <math.h>

#define GELU(v) (0.5f * (v) * (1.0f + erff((v)*0.70710678118654752440f)))

typedef __attribute__((ext_vector_type(8))) short short8;
typedef __attribute__((ext_vector_type(4))) float f32x4;
typedef __attribute__((ext_vector_type(16))) float f32x16;
#define MFMA16 __builtin_amdgcn_mfma_f32_16x16x32_bf16
#define MFMA32 __builtin_amdgcn_mfma_f32_32x32x16_bf16

// Exact 3-way bf16 split of fp32 (24 = 3x8 mantissa bits, truncation):
// v == p1 + p2 + p3 exactly (each pi representable in bf16).
#define SPLIT3(V, U1, U2, U3)                                                  \
  unsigned U1 = __float_as_uint(V) & 0xFFFF0000u;                              \
  float _r1 = (V)-__uint_as_float(U1);                                         \
  unsigned U2 = __float_as_uint(_r1) & 0xFFFF0000u;                            \
  float _r2 = _r1 - __uint_as_float(U2);                                       \
  unsigned U3 = __float_as_uint(_r2) & 0xFFFF0000u;

#define H1PL 8388608  // h1s plane stride in shorts: 32b x 128 x 128 x 16

// ---------------- Setup: fold weights + split codebook/enc2/dec1 weights -------
__global__ __launch_bounds__(256) void k_fold(const float* __restrict__ e2w,
                                              const float* __restrict__ d1w,
                                              const float* __restrict__ d2w,
                                              const float* __restrict__ cb,
                                              float* __restrict__ fwd2,
                                              unsigned short* __restrict__ cbs,
                                              float* __restrict__ csqg,
                                              unsigned short* __restrict__ wfrag,
                                              unsigned short* __restrict__ wfd1,
                                              float* __restrict__ lossout) {
  int i = blockIdx.x * 256 + threadIdx.x;
  if (i == 0) lossout[0] = 0.f;  // k_vq accumulates atomically (stream-ordered)
  if (i < 256) {
    int j = i;
    int pt = j & 15, ic = j >> 4;
    int a = pt >> 3, b2 = (pt >> 2) & 1, dy = (pt >> 1) & 1, dx = pt & 1;
    const float* wsrc = d2w + ic * 9;
    float s = 0.f;
    for (int ky = 0; ky < 3; ++ky) {
      int rm = (a == 0) ? (ky == 0 ? 0 : 1) : (ky == 2 ? 1 : 0);
      if (rm != dy) continue;
      for (int kx = 0; kx < 3; ++kx) {
        int cm = (b2 == 0) ? (kx == 0 ? 0 : 1) : (kx == 2 ? 1 : 0);
        if (cm == dx) s += wsrc[ky * 3 + kx];
      }
    }
    fwd2[j] = s;
  } else if (i < 16640) {
    int j = i - 256;  // [0, 16384): code = j>>5, ch = j&31
    float v = cb[j];
    SPLIT3(v, u1, u2, u3)
    cbs[j] = (unsigned short)(u1 >> 16);
    cbs[16384 + j] = (unsigned short)(u2 >> 16);
    cbs[32768 + j] = (unsigned short)(u3 >> 16);
  } else if (i < 17152) {
    int c = i - 16640;
    const float* row = cb + (size_t)c * 32;
    float s = 0.f;
#pragma unroll
    for (int d = 0; d < 32; ++d) s = fmaf(row[d], row[d], s);
    csqg[c] = s;
  } else if (i < 30976) {
    int j = i - 17152;  // [0, 13824)
    int p = j / 4608, rem = j - p * 4608;
    int t = rem >> 9, l2 = (rem >> 3) & 63, jj = rem & 7;
    float v = e2w[((l2 & 31) * 16 + ((l2 >> 5) * 8 + jj)) * 9 + t];
    SPLIT3(v, u1, u2, u3)
    unsigned short r = (p == 0)   ? (unsigned short)(u1 >> 16)
                       : (p == 1) ? (unsigned short)(u2 >> 16)
                                  : (unsigned short)(u3 >> 16);
    wfrag[j] = r;
  } else if (i < 86272) {
    int j = i - 30976;  // [0, 55296)
    int slot = j >> 9, l2 = (j >> 3) & 63, jj = j & 7;
    int cx = slot / 36, rem = slot % 36;
    int r3 = rem / 12, rem2 = rem % 12;
    int kh = rem2 / 6, rem3 = rem2 % 6;
    int pp = rem3 / 3, part = rem3 % 3;
    int c = l2 & 31, hi = l2 >> 5;
    int oc = c & 15, b2 = c >> 4;
    int ic = kh * 16 + hi * 8 + jj;
    int dy = r3 - pp, dx = cx - b2;
    float s = 0.f;
    if ((unsigned)dy < 2u && (unsigned)dx < 2u) {
      const float* wsrc = d1w + (oc * 32 + ic) * 9;
      for (int ky = 0; ky < 3; ++ky) {
        int rm = (pp == 0) ? (ky == 0 ? 0 : 1) : (ky == 2 ? 1 : 0);
        if (rm != dy) continue;
        for (int kx = 0; kx < 3; ++kx) {
          int cm = (b2 == 0) ? (kx == 0 ? 0 : 1) : (kx == 2 ? 1 : 0);
          if (cm == dx) s += wsrc[ky * 3 + kx];
        }
      }
    }
    SPLIT3(s, u1, u2, u3)
    unsigned short r = (part == 0)   ? (unsigned short)(u1 >> 16)
                       : (part == 1) ? (unsigned short)(u2 >> 16)
                                     : (unsigned short)(u3 >> 16);
    wfd1[j] = r;
  }
}

// ---------------- Kernel A: conv1 (1->16) + maxpool2 + gelu --------------------
// (r14: emits h1 pre-split as 3 bf16 planes; r12 XCD-slab mapping.)
__global__ __launch_bounds__(256) void k_enc1(const float* __restrict__ x,
                                              const float* __restrict__ w,
                                              const float* __restrict__ bias,
                                              unsigned short* __restrict__ h1s) {
  int n = blockIdx.x;
  int ysl = n & 7, m = n >> 3;
  int b = m & 31, k = m >> 5;
  int yy = ysl * 16 + k * 2 + (threadIdx.x >> 7);
  int xx = threadIdx.x & 127;
  const float* xp = x + (size_t)b * 65536;
  int r0 = 2 * yy - 1, c0 = 2 * xx - 1;
  float in[4][4];
#pragma unroll
  for (int i = 0; i < 4; ++i) {
    int r = r0 + i;
    bool rv = (unsigned)r < 256u;
#pragma unroll
    for (int j = 0; j < 4; ++j) {
      int c = c0 + j;
      in[i][j] = (rv && (unsigned)c < 256u) ? xp[r * 256 + c] : 0.0f;
    }
  }
  short8 p1[2], p2[2], p3[2];
#pragma unroll
  for (int oc = 0; oc < 16; ++oc) {
    const float* wp = w + oc * 9;  // uniform -> s_load
    float s00 = 0.f, s01 = 0.f, s10 = 0.f, s11 = 0.f;
#pragma unroll
    for (int ky = 0; ky < 3; ++ky)
#pragma unroll
      for (int kx = 0; kx < 3; ++kx) {
        float wv = wp[ky * 3 + kx];
        s00 = fmaf(in[ky][kx], wv, s00);
        s01 = fmaf(in[ky][kx + 1], wv, s01);
        s10 = fmaf(in[ky + 1][kx], wv, s10);
        s11 = fmaf(in[ky + 1][kx + 1], wv, s11);
      }
    float mm = fmaxf(fmaxf(s00, s01), fmaxf(s10, s11)) + bias[oc];
    float g = GELU(mm);
    SPLIT3(g, u1, u2, u3)
    p1[oc >> 3][oc & 7] = (short)(u1 >> 16);
    p2[oc >> 3][oc & 7] = (short)(u2 >> 16);
    p3[oc >> 3][oc & 7] = (short)(u3 >> 16);
  }
  unsigned short* op = h1s + (size_t)b * 262144 + ((size_t)yy * 128 + xx) * 16;
  *(short8*)(op) = p1[0];
  *(short8*)(op + 8) = p1[1];
  *(short8*)(op + H1PL) = p2[0];
  *(short8*)(op + H1PL + 8) = p2[1];
  *(short8*)(op + 2 * H1PL) = p3[0];
  *(short8*)(op + 2 * H1PL + 8) = p3[1];
}

// ---------------- Kernel B: conv2 (16->32) + maxpool2 via split MFMA -----------
// (r14: pure 16B-copy staging from pre-split h1s; r12 XCD-matched grid.)
__global__ __launch_bounds__(256) void k_enc2(const unsigned short* __restrict__ h1s,
                                              const unsigned short* __restrict__ wfrag,
                                              const float* __restrict__ bias,
                                              float* __restrict__ h2) {
  __shared__ __align__(16) unsigned short sA[3 * 2 * 10 * 34 * 8];  // 32640 B
  const int PP = 2 * 10 * 34 * 8;
  int tid = threadIdx.x;
  int n = blockIdx.x;
  int xcd = n & 7, m = n >> 3;
  int ty = xcd * 2 + (m & 1);
  int q0 = m >> 1;
  int b = q0 >> 2, xt = q0 & 3;
  int X0 = xt * 32, Y0 = ty * 8;
  const unsigned short* ip = h1s + (size_t)b * 262144;
  for (int g = tid; g < 680; g += 256) {  // pos(340) x ich(2) granule-groups
    int pos = g >> 1, ich = g & 1;
    int yy = pos / 34, xx = pos - yy * 34;
    int y = Y0 - 1 + yy, xg = X0 - 1 + xx;
    short8 v1 = {0, 0, 0, 0, 0, 0, 0, 0};
    short8 v2 = {0, 0, 0, 0, 0, 0, 0, 0};
    short8 v3 = {0, 0, 0, 0, 0, 0, 0, 0};
    if ((unsigned)y < 128u && (unsigned)xg < 128u) {
      const unsigned short* sp = ip + ((size_t)y * 128 + xg) * 16 + ich * 8;
      v1 = *(const short8*)(sp);
      v2 = *(const short8*)(sp + H1PL);
      v3 = *(const short8*)(sp + 2 * H1PL);
    }
    int si = ((ich * 10 + yy) * 34 + xx) * 8;
    *(short8*)(sA + si) = v1;
    *(short8*)(sA + PP + si) = v2;
    *(short8*)(sA + 2 * PP + si) = v3;
  }
  __syncthreads();

  int l = tid & 63, w = tid >> 6;
  int xl = l & 31, ich = l >> 5;
  f32x16 acc0[2], acc1[2];
#pragma unroll
  for (int s = 0; s < 2; ++s)
#pragma unroll
    for (int r = 0; r < 16; ++r) { acc0[s][r] = 0.f; acc1[s][r] = 0.f; }

#pragma unroll
  for (int t = 0; t < 9; ++t) {
    int dy = t / 3, dx = t % 3;
    int s = t & 1;
    const unsigned short* wb = wfrag + t * 512 + l * 8;
    short8 bf1 = *(const short8*)(wb);
    short8 bf2 = *(const short8*)(wb + 4608);
    short8 bf3 = *(const short8*)(wb + 9216);
    int g0 = ((ich * 10) + (2 * w + dy)) * 34 + xl + dx;
    const unsigned short* a0p = sA + g0 * 8;
    short8 a01 = *(const short8*)(a0p);
    short8 a02 = *(const short8*)(a0p + PP);
    short8 a03 = *(const short8*)(a0p + 2 * PP);
    const unsigned short* a1p = a0p + 34 * 8;
    short8 a11 = *(const short8*)(a1p);
    short8 a12 = *(const short8*)(a1p + PP);
    short8 a13 = *(const short8*)(a1p + 2 * PP);
    acc0[s] = MFMA32(a01, bf1, acc0[s], 0, 0, 0);
    acc0[s] = MFMA32(a01, bf2, acc0[s], 0, 0, 0);
    acc0[s] = MFMA32(a02, bf1, acc0[s], 0, 0, 0);
    acc0[s] = MFMA32(a02, bf2, acc0[s], 0, 0, 0);
    acc0[s] = MFMA32(a01, bf3, acc0[s], 0, 0, 0);
    acc0[s] = MFMA32(a03, bf1, acc0[s], 0, 0, 0);
    acc1[s] = MFMA32(a11, bf1, acc1[s], 0, 0, 0);
    acc1[s] = MFMA32(a11, bf2, acc1[s], 0, 0, 0);
    acc1[s] = MFMA32(a12, bf1, acc1[s], 0, 0, 0);
    acc1[s] = MFMA32(a12, bf2, acc1[s], 0, 0, 0);
    acc1[s] = MFMA32(a11, bf3, acc1[s], 0, 0, 0);
    acc1[s] = MFMA32(a13, bf1, acc1[s], 0, 0, 0);
  }

  float bv = bias[l & 31];
  int ypool = (Y0 >> 1) + w;
  float* op = h2 + (size_t)b * 131072 + (size_t)(l & 31) * 4096 + ypool * 64 + (X0 >> 1);
#pragma unroll
  for (int k = 0; k < 8; ++k) {
    float e0 = (acc0[0][2 * k] + acc0[1][2 * k]);
    float o0 = (acc0[0][2 * k + 1] + acc0[1][2 * k + 1]);
    float e1 = (acc1[0][2 * k] + acc1[1][2 * k]);
    float o1 = (acc1[0][2 * k + 1] + acc1[1][2 * k + 1]);
    float mm = fmaxf(fmaxf(e0, o0), fmaxf(e1, o1)) + bv;
    int row = ((2 * k) & 3) + 8 * ((2 * k) >> 2) + 4 * ich;
    op[row >> 1] = mm;
  }
}

// ---------------- Kernel C: VQ via exact-split bf16 MFMA (v3) ------------------
// r15: (a) direct register staging — lane loads its OWN A-fragment data from h2
// (16 consecutive tokens per cl-group -> coalesced 64B), SPLIT3 in-reg; the LDS
// [tok][ch] transpose + 2 barriers + 61KB LDS are deleted. (b) 32 tokens/wave
// (TQ=2) -> 1024 blocks -> 4 blocks/CU -> 16 waves/CU (2x TLP for B-latency).
// fsq totals via shfl_xor(16/32) across the 4 k-groups of each token.
__global__ __launch_bounds__(256, 4) void k_vq(const float* __restrict__ h2,
                                               const unsigned short* __restrict__ cbs,
                                               const float* __restrict__ csqg,
                                               float* __restrict__ idxout,
                                               float* __restrict__ lossout) {
  __shared__ float sFsq[128];
  __shared__ float sBd[128];
  __shared__ int sBi[128];
  __shared__ float sred[2];
  int tid = threadIdx.x;
  int blk = blockIdx.x;
  int t0 = blk * 128;  // 32 blocks/batch: no batch straddle
  size_t abase = (size_t)(t0 >> 12) * 131072 + (t0 & 4095);

  int l = tid & 63, w = tid >> 6;
  int cl = l & 15, k0 = (l >> 4) * 8;

  // ---- direct staging: 2 tq x 8 ch per lane, split in-reg ----
  short8 af1[2], af2[2], af3[2];
  float fsq[2];
#pragma unroll
  for (int tq = 0; tq < 2; ++tq) {
    const float* src = h2 + abase + w * 32 + tq * 16 + cl;
    float fs = 0.f;
#pragma unroll
    for (int e = 0; e < 8; ++e) {
      float v = src[(size_t)(k0 + e) * 4096];
      fs = fmaf(v, v, fs);
      SPLIT3(v, u1, u2, u3)
      af1[tq][e] = (short)(u1 >> 16);
      af2[tq][e] = (short)(u2 >> 16);
      af3[tq][e] = (short)(u3 >> 16);
    }
    fsq[tq] = fs;
  }
#pragma unroll
  for (int tq = 0; tq < 2; ++tq) {  // total over the 4 k-groups of each token
    fsq[tq] += __shfl_xor(fsq[tq], 16, 64);
    fsq[tq] += __shfl_xor(fsq[tq], 32, 64);
  }
  if (l < 16) {
    sFsq[w * 32 + l] = fsq[0];
    sFsq[w * 32 + 16 + l] = fsq[1];
  }

  float bd[2][4];
  int bi[2][4];
#pragma unroll
  for (int a = 0; a < 2; ++a)
#pragma unroll
    for (int b = 0; b < 4; ++b) { bd[a][b] = 3.4e38f; bi[a][b] = 0; }

#define LOADB(S, CT)                                                           \
  {                                                                            \
    int col = (CT)*16 + cl;                                                    \
    b1##S = *(const short8*)(cbs + (0 * 512 + col) * 32 + k0);                 \
    b2##S = *(const short8*)(cbs + (1 * 512 + col) * 32 + k0);                 \
    b3##S = *(const short8*)(cbs + (2 * 512 + col) * 32 + k0);                 \
    cq##S = csqg[col];                                                         \
  }
#define COMPUTE(S, CT)                                                         \
  {                                                                            \
    _Pragma("unroll") for (int tq = 0; tq < 2; ++tq) {                         \
      f32x4 acc = {0.f, 0.f, 0.f, 0.f};                                        \
      acc = MFMA16(af1[tq], b1##S, acc, 0, 0, 0);                              \
      acc = MFMA16(af1[tq], b2##S, acc, 0, 0, 0);                              \
      acc = MFMA16(af2[tq], b1##S, acc, 0, 0, 0);                              \
      acc = MFMA16(af2[tq], b2##S, acc, 0, 0, 0);                              \
      acc = MFMA16(af1[tq], b3##S, acc, 0, 0, 0);                              \
      acc = MFMA16(af3[tq], b1##S, acc, 0, 0, 0);                              \
      _Pragma("unroll") for (int i = 0; i < 4; ++i) {                          \
        float d = fmaf(-2.f, acc[i], cq##S);                                   \
        if (d < bd[tq][i]) { bd[tq][i] = d; bi[tq][i] = (CT)*16 + cl; }        \
      }                                                                        \
    }                                                                          \
  }

  short8 b1A, b2A, b3A, b1B, b2B, b3B;
  float cqA, cqB;
  LOADB(A, 0)
  LOADB(B, 1)
#pragma unroll 1
  for (int ct = 0; ct < 32; ct += 2) {
    COMPUTE(A, ct)
    LOADB(A, (ct + 2) & 31)  // distance-2 prefetch; wrap: in-bounds, unused
    COMPUTE(B, ct + 1)
    LOADB(B, (ct + 3) & 31)
  }
#undef LOADB
#undef COMPUTE

  // ---- cross-lane argmin over 16 code-slices (lexicographic) ----
#pragma unroll
  for (int tq = 0; tq < 2; ++tq)
#pragma unroll
    for (int i = 0; i < 4; ++i)
#pragma unroll
      for (int m = 1; m < 16; m <<= 1) {
        float od = __shfl_xor(bd[tq][i], m, 64);
        int ob = __shfl_xor(bi[tq][i], m, 64);
        if (od < bd[tq][i] || (od == bd[tq][i] && ob < bi[tq][i])) {
          bd[tq][i] = od;
          bi[tq][i] = ob;
        }
      }
  if (cl == 0) {
#pragma unroll
    for (int tq = 0; tq < 2; ++tq)
#pragma unroll
      for (int i = 0; i < 4; ++i) {
        int tokl = w * 32 + tq * 16 + (l >> 4) * 4 + i;
        sBi[tokl] = bi[tq][i];
        sBd[tokl] = bd[tq][i];
      }
  }
  __syncthreads();

  if (tid < 128) {
    idxout[t0 + tid] = (float)sBi[tid];
    float loss = sBd[tid] + sFsq[tid];  // ||q-f||^2 = csq - 2 f.c + ||f||^2
#pragma unroll
    for (int off = 32; off > 0; off >>= 1) loss += __shfl_down(loss, off, 64);
    if ((tid & 63) == 0) sred[tid >> 6] = loss;
  }
  __syncthreads();
  if (tid == 0) atomicAdd(lossout, (sred[0] + sred[1]) * (1.0f / 4194304.0f));
}

// ---------------- Kernel D: up2 + conv (32->16) + gelu via split MFMA ----------
// (r13-verified: gather-direct A, 1 q-row/wave, interleaved d1o.)
__global__ __launch_bounds__(256) void k_dec1(const float* __restrict__ idxf,
                                              const unsigned short* __restrict__ cbs,
                                              const unsigned short* __restrict__ wfd1,
                                              const float* __restrict__ bias,
                                              float* __restrict__ o) {
  __shared__ int sIdx[204];  // 6 halo rows x 34 cols
  int tid = threadIdx.x;
  int b = blockIdx.y;
  int qx0 = (blockIdx.x & 1) * 32, qy0 = (blockIdx.x >> 1) * 4;
  const float* ib = idxf + (size_t)b * 4096;
  if (tid < 204) {
    int yy = tid / 34, xx = tid % 34;
    int y = qy0 - 1 + yy, x = qx0 - 1 + xx;
    sIdx[tid] = ((unsigned)y < 64u && (unsigned)x < 64u) ? (int)ib[y * 64 + x] : -1;
  }
  __syncthreads();

  int l = tid & 63, w = tid >> 6;  // wave w -> output q-row qy0+w
  int xl = l & 31, hi = l >> 5;
  f32x16 acc[2];  // [p2 = output row phase]
#pragma unroll
  for (int p2 = 0; p2 < 2; ++p2)
#pragma unroll
    for (int r = 0; r < 16; ++r) acc[p2][r] = 0.f;

#pragma unroll
  for (int cx = 0; cx < 3; ++cx) {
#pragma unroll
    for (int kh = 0; kh < 2; ++kh) {
      short8 Bf[4][3];  // q=(ry,pq) packed: 0:(0,0) 1:(1,0) 2:(1,1) 3:(2,1)
#pragma unroll
      for (int q = 0; q < 4; ++q) {
        int r3 = (q == 0) ? 0 : (q == 3) ? 2 : 1;
        int pq = (q >= 2) ? 1 : 0;
#pragma unroll
        for (int pt = 0; pt < 3; ++pt) {
          int slot = cx * 36 + r3 * 12 + kh * 6 + pq * 3 + pt;
          Bf[q][pt] = *(const short8*)(wfd1 + (size_t)slot * 512 + l * 8);
        }
      }
#pragma unroll
      for (int ry = 0; ry < 3; ++ry) {
        int idx = sIdx[(w + ry) * 34 + xl + cx];
        short8 a1 = {0, 0, 0, 0, 0, 0, 0, 0};
        short8 a2 = {0, 0, 0, 0, 0, 0, 0, 0};
        short8 a3 = {0, 0, 0, 0, 0, 0, 0, 0};
        if (idx >= 0) {
          const unsigned short* ap = cbs + (size_t)idx * 32 + kh * 16 + hi * 8;
          a1 = *(const short8*)(ap);
          a2 = *(const short8*)(ap + 16384);
          a3 = *(const short8*)(ap + 32768);
        }
#pragma unroll
        for (int p2 = 0; p2 < 2; ++p2) {
          if ((ry == 0 && p2 == 1) || (ry == 2 && p2 == 0)) continue;
          int q = ry + p2;
          f32x16 t = acc[p2];
          t = MFMA32(a1, Bf[q][0], t, 0, 0, 0);
          t = MFMA32(a1, Bf[q][1], t, 0, 0, 0);
          t = MFMA32(a2, Bf[q][0], t, 0, 0, 0);
          t = MFMA32(a2, Bf[q][1], t, 0, 0, 0);
          t = MFMA32(a1, Bf[q][2], t, 0, 0, 0);
          t = MFMA32(a3, Bf[q][0], t, 0, 0, 0);
          acc[p2] = t;
        }
      }
    }
  }

  float bv = bias[l & 15];
  int b2 = (l >> 4) & 1;
  int oc = l & 15;
  int qy = qy0 + w;
  float* ob = o + (size_t)b * 262144;
#pragma unroll
  for (int p2 = 0; p2 < 2; ++p2) {
    int Y = 2 * qy + p2;
#pragma unroll
    for (int reg = 0; reg < 16; ++reg) {
      int rowval = (reg & 3) + 8 * (reg >> 2) + 4 * hi;
      int X = qx0 * 2 + 2 * rowval + b2;
      ob[((size_t)Y * 128 + X) * 16 + oc] = GELU(acc[p2][reg] + bv);
    }
  }
}

// ---------------- Kernel E: up2 + conv (16->1) + clip, phase-folded ------------
// (r13-verified: interleaved input, position-major LDS [pos][17].)
__device__ __forceinline__ void d2_loadi3(float (&dst)[3][3], const float* t) {
#pragma unroll
  for (int dy = 0; dy < 3; ++dy)
#pragma unroll
    for (int dx = 0; dx < 3; ++dx) dst[dy][dx] = t[(dy * 18 + dx) * 17];
}
__global__ __launch_bounds__(256) void k_dec2(const float* __restrict__ d1,
                                              const float* __restrict__ fwd2,
                                              const float* __restrict__ bias,
                                              float* __restrict__ out) {
  __shared__ float st[18 * 18 * 17];  // [row][col][ic16 + pad]
  int tid = threadIdx.x;
  int b = blockIdx.y;
  int R0 = (blockIdx.x >> 3) * 16, C0 = (blockIdx.x & 7) * 16;
  const float* ip = d1 + (size_t)b * 262144;
  for (int i = tid; i < 1296; i += 256) {  // 324 pos x 4 ic-quads
    int pos = i >> 2, q = i & 3;
    int rr = pos / 18, cc = pos % 18;
    int r = R0 - 1 + rr, c = C0 - 1 + cc;
    float4 v = {0.f, 0.f, 0.f, 0.f};
    if ((unsigned)r < 128u && (unsigned)c < 128u)
      v = *(const float4*)(ip + ((size_t)r * 128 + c) * 16 + q * 4);
    float* dp = st + (rr * 18 + cc) * 17 + q * 4;
    dp[0] = v.x; dp[1] = v.y; dp[2] = v.z; dp[3] = v.w;
  }
  __syncthreads();
  int lane = tid & 63, wid = tid >> 6;
  int qy = wid >> 1, qx = wid & 1;
  int ty = qy * 8 + (lane >> 3), tx = qx * 8 + (lane & 7);
  float acc[4] = {0.f, 0.f, 0.f, 0.f};
  const float* tb = st + (ty * 18 + tx) * 17;
  float i3A[3][3], i3B[3][3];
  d2_loadi3(i3A, tb);
#pragma unroll 1
  for (int ic = 0; ic < 16; ic += 2) {
    d2_loadi3(i3B, tb + (ic + 1));
    {
      const float* wp = fwd2 + ic * 16;  // scalar loads
#pragma unroll
      for (int p = 0; p < 4; ++p) {
        int a = p >> 1, b2 = p & 1;
#pragma unroll
        for (int tp = 0; tp < 4; ++tp) {
          int dy = tp >> 1, dx = tp & 1;
          acc[p] = fmaf(i3A[a + dy][b2 + dx], wp[p * 4 + tp], acc[p]);
        }
      }
    }
    d2_loadi3(i3A, tb + ((ic + 2) & 15));  // wrap: harmless re-read
    {
      const float* wp = fwd2 + (ic + 1) * 16;
#pragma unroll
      for (int p = 0; p < 4; ++p) {
        int a = p >> 1, b2 = p & 1;
#pragma unroll
        for (int tp = 0; tp < 4; ++tp) {
          int dy = tp >> 1, dx = tp & 1;
          acc[p] = fmaf(i3B[a + dy][b2 + dx], wp[p * 4 + tp], acc[p]);
        }
      }
    }
  }
  float bv = bias[0];
  int Y = 2 * (R0 + ty), X = 2 * (C0 + tx);
  float* op = out + (size_t)b * 65536 + Y * 256 + X;
  float2 r0v, r1v;
  r0v.x = fminf(1.0f, fmaxf(-1.0f, acc[0] + bv));
  r0v.y = fminf(1.0f, fmaxf(-1.0f, acc[1] + bv));
  r1v.x = fminf(1.0f, fmaxf(-1.0f, acc[2] + bv));
  r1v.y = fminf(1.0f, fmaxf(-1.0f, acc[3] + bv));
  *(float2*)op = r0v;
  *(float2*)(op + 256) = r1v;
}

extern "C" void kernel_launch(void* const* d_in, const int* in_sizes, int n_in,
                              void* d_out, int out_size, void* d_ws, size_t ws_size,
                              hipStream_t stream) {
  const float* x   = (const float*)d_in[0];
  const float* e1w = (const float*)d_in[1];
  const float* e1b = (const float*)d_in[2];
  const float* e2w = (const float*)d_in[3];
  const float* e2b = (const float*)d_in[4];
  const float* cb  = (const float*)d_in[5];
  const float* d1w = (const float*)d_in[6];
  const float* d1b = (const float*)d_in[7];
  const float* d2w = (const float*)d_in[8];
  const float* d2b = (const float*)d_in[9];

  float* out = (float*)d_out;
  float* y       = out;                       // [32,1,256,256] = 2097152
  float* idxout  = out + 2097152;             // [32,64,64]     = 131072 (as float)
  float* lossout = out + 2097152 + 131072;    // scalar

  // Workspace layout:
  //  h1s: 3 bf16 planes, 3 x 8388608 shorts = 12582912 floats  [0, 12582912)
  //  h2 : fp32 [32][32][64][64]                                [12582912, 16777216)
  //  fwd2: 256 floats                                          [16777216, ...)
  //  d1o: fp32 [32][128][128][16], reuses h1s region (dead after enc2)
  float* ws = (float*)d_ws;
  unsigned short* h1s = (unsigned short*)ws;
  float* h2      = ws + 12582912;
  float* fwd2    = ws + 16777216;
  float* d1o     = ws;  // 8388608 floats, fits in h1s region

  // Scratch in the y-region of out (written by k_fold, consumed before k_dec2
  // overwrites all of y): cbs 24576f, csqg 512f, wfrag 6912f, wfd1 27648f.
  unsigned short* cbs = (unsigned short*)out;              // 49152 bf16
  float* csqg = out + 24576;                               // 512
  unsigned short* wfrag = (unsigned short*)(out + 25088);  // 13824 bf16
  unsigned short* wfd1 = (unsigned short*)(out + 32000);   // 55296 bf16

  k_fold<<<dim3(337), 256, 0, stream>>>(e2w, d1w, d2w, cb, fwd2, cbs, csqg, wfrag, wfd1, lossout);
  k_enc1<<<dim3(2048), 256, 0, stream>>>(x, e1w, e1b, h1s);
  k_enc2<<<dim3(2048), 256, 0, stream>>>(h1s, wfrag, e2b, h2);
  k_vq<<<dim3(1024), 256, 0, stream>>>(h2, cbs, csqg, idxout, lossout);
  k_dec1<<<dim3(32, 32), 256, 0, stream>>>(idxout, cbs, wfd1, d1b, d1o);
  k_dec2<<<dim3(64, 32), 256, 0, stream>>>(d1o, fwd2, d2b, y);
}

// Round 17
// 210.989 us; speedup vs baseline: 1.0378x; 1.0378x over previous
//
#include <hip/hip_runtime.h>
#include <math.h>

#define GELU(v) (0.5f * (v) * (1.0f + erff((v)*0.70710678118654752440f)))

typedef __attribute__((ext_vector_type(8))) short short8;
typedef __attribute__((ext_vector_type(4))) float f32x4;
typedef __attribute__((ext_vector_type(16))) float f32x16;
#define MFMA16 __builtin_amdgcn_mfma_f32_16x16x32_bf16
#define MFMA32 __builtin_amdgcn_mfma_f32_32x32x16_bf16

// Exact 3-way bf16 split of fp32 (24 = 3x8 mantissa bits, truncation):
// v == p1 + p2 + p3 exactly (each pi representable in bf16).
#define SPLIT3(V, U1, U2, U3)                                                  \
  unsigned U1 = __float_as_uint(V) & 0xFFFF0000u;                              \
  float _r1 = (V)-__uint_as_float(U1);                                         \
  unsigned U2 = __float_as_uint(_r1) & 0xFFFF0000u;                            \
  float _r2 = _r1 - __uint_as_float(U2);                                       \
  unsigned U3 = __float_as_uint(_r2) & 0xFFFF0000u;

#define H1PL 8388608  // h1s plane stride in shorts: 32b x 128 x 128 x 16

// ---------------- Setup: fold weights + split codebook/enc2/dec1 weights -------
__global__ __launch_bounds__(256) void k_fold(const float* __restrict__ e2w,
                                              const float* __restrict__ d1w,
                                              const float* __restrict__ d2w,
                                              const float* __restrict__ cb,
                                              float* __restrict__ fwd2,
                                              unsigned short* __restrict__ cbs,
                                              float* __restrict__ csqg,
                                              unsigned short* __restrict__ wfrag,
                                              unsigned short* __restrict__ wfd1,
                                              float* __restrict__ lossout) {
  int i = blockIdx.x * 256 + threadIdx.x;
  if (i == 0) lossout[0] = 0.f;  // k_vq accumulates atomically (stream-ordered)
  if (i < 256) {
    int j = i;
    int pt = j & 15, ic = j >> 4;
    int a = pt >> 3, b2 = (pt >> 2) & 1, dy = (pt >> 1) & 1, dx = pt & 1;
    const float* wsrc = d2w + ic * 9;
    float s = 0.f;
    for (int ky = 0; ky < 3; ++ky) {
      int rm = (a == 0) ? (ky == 0 ? 0 : 1) : (ky == 2 ? 1 : 0);
      if (rm != dy) continue;
      for (int kx = 0; kx < 3; ++kx) {
        int cm = (b2 == 0) ? (kx == 0 ? 0 : 1) : (kx == 2 ? 1 : 0);
        if (cm == dx) s += wsrc[ky * 3 + kx];
      }
    }
    fwd2[j] = s;
  } else if (i < 16640) {
    int j = i - 256;  // [0, 16384): code = j>>5, ch = j&31
    float v = cb[j];
    SPLIT3(v, u1, u2, u3)
    cbs[j] = (unsigned short)(u1 >> 16);
    cbs[16384 + j] = (unsigned short)(u2 >> 16);
    cbs[32768 + j] = (unsigned short)(u3 >> 16);
  } else if (i < 17152) {
    int c = i - 16640;
    const float* row = cb + (size_t)c * 32;
    float s = 0.f;
#pragma unroll
    for (int d = 0; d < 32; ++d) s = fmaf(row[d], row[d], s);
    csqg[c] = s;
  } else if (i < 30976) {
    int j = i - 17152;  // [0, 13824)
    int p = j / 4608, rem = j - p * 4608;
    int t = rem >> 9, l2 = (rem >> 3) & 63, jj = rem & 7;
    float v = e2w[((l2 & 31) * 16 + ((l2 >> 5) * 8 + jj)) * 9 + t];
    SPLIT3(v, u1, u2, u3)
    unsigned short r = (p == 0)   ? (unsigned short)(u1 >> 16)
                       : (p == 1) ? (unsigned short)(u2 >> 16)
                                  : (unsigned short)(u3 >> 16);
    wfrag[j] = r;
  } else if (i < 86272) {
    int j = i - 30976;  // [0, 55296)
    int slot = j >> 9, l2 = (j >> 3) & 63, jj = j & 7;
    int cx = slot / 36, rem = slot % 36;
    int r3 = rem / 12, rem2 = rem % 12;
    int kh = rem2 / 6, rem3 = rem2 % 6;
    int pp = rem3 / 3, part = rem3 % 3;
    int c = l2 & 31, hi = l2 >> 5;
    int oc = c & 15, b2 = c >> 4;
    int ic = kh * 16 + hi * 8 + jj;
    int dy = r3 - pp, dx = cx - b2;
    float s = 0.f;
    if ((unsigned)dy < 2u && (unsigned)dx < 2u) {
      const float* wsrc = d1w + (oc * 32 + ic) * 9;
      for (int ky = 0; ky < 3; ++ky) {
        int rm = (pp == 0) ? (ky == 0 ? 0 : 1) : (ky == 2 ? 1 : 0);
        if (rm != dy) continue;
        for (int kx = 0; kx < 3; ++kx) {
          int cm = (b2 == 0) ? (kx == 0 ? 0 : 1) : (kx == 2 ? 1 : 0);
          if (cm == dx) s += wsrc[ky * 3 + kx];
        }
      }
    }
    SPLIT3(s, u1, u2, u3)
    unsigned short r = (part == 0)   ? (unsigned short)(u1 >> 16)
                       : (part == 1) ? (unsigned short)(u2 >> 16)
                                     : (unsigned short)(u3 >> 16);
    wfd1[j] = r;
  }
}

// ---------------- Kernel A: conv1 (1->16) + maxpool2 + gelu --------------------
// (r14: emits h1 pre-split as 3 bf16 planes; r12 XCD-slab mapping.)
__global__ __launch_bounds__(256) void k_enc1(const float* __restrict__ x,
                                              const float* __restrict__ w,
                                              const float* __restrict__ bias,
                                              unsigned short* __restrict__ h1s) {
  int n = blockIdx.x;
  int ysl = n & 7, m = n >> 3;
  int b = m & 31, k = m >> 5;
  int yy = ysl * 16 + k * 2 + (threadIdx.x >> 7);
  int xx = threadIdx.x & 127;
  const float* xp = x + (size_t)b * 65536;
  int r0 = 2 * yy - 1, c0 = 2 * xx - 1;
  float in[4][4];
#pragma unroll
  for (int i = 0; i < 4; ++i) {
    int r = r0 + i;
    bool rv = (unsigned)r < 256u;
#pragma unroll
    for (int j = 0; j < 4; ++j) {
      int c = c0 + j;
      in[i][j] = (rv && (unsigned)c < 256u) ? xp[r * 256 + c] : 0.0f;
    }
  }
  short8 p1[2], p2[2], p3[2];
#pragma unroll
  for (int oc = 0; oc < 16; ++oc) {
    const float* wp = w + oc * 9;  // uniform -> s_load
    float s00 = 0.f, s01 = 0.f, s10 = 0.f, s11 = 0.f;
#pragma unroll
    for (int ky = 0; ky < 3; ++ky)
#pragma unroll
      for (int kx = 0; kx < 3; ++kx) {
        float wv = wp[ky * 3 + kx];
        s00 = fmaf(in[ky][kx], wv, s00);
        s01 = fmaf(in[ky][kx + 1], wv, s01);
        s10 = fmaf(in[ky + 1][kx], wv, s10);
        s11 = fmaf(in[ky + 1][kx + 1], wv, s11);
      }
    float mm = fmaxf(fmaxf(s00, s01), fmaxf(s10, s11)) + bias[oc];
    float g = GELU(mm);
    SPLIT3(g, u1, u2, u3)
    p1[oc >> 3][oc & 7] = (short)(u1 >> 16);
    p2[oc >> 3][oc & 7] = (short)(u2 >> 16);
    p3[oc >> 3][oc & 7] = (short)(u3 >> 16);
  }
  unsigned short* op = h1s + (size_t)b * 262144 + ((size_t)yy * 128 + xx) * 16;
  *(short8*)(op) = p1[0];
  *(short8*)(op + 8) = p1[1];
  *(short8*)(op + H1PL) = p2[0];
  *(short8*)(op + H1PL + 8) = p2[1];
  *(short8*)(op + 2 * H1PL) = p3[0];
  *(short8*)(op + 2 * H1PL + 8) = p3[1];
}

// ---------------- Kernel B: conv2 (16->32) + maxpool2 via split MFMA -----------
// (r14: pure 16B-copy staging from pre-split h1s; r12 XCD-matched grid.)
__global__ __launch_bounds__(256) void k_enc2(const unsigned short* __restrict__ h1s,
                                              const unsigned short* __restrict__ wfrag,
                                              const float* __restrict__ bias,
                                              float* __restrict__ h2) {
  __shared__ __align__(16) unsigned short sA[3 * 2 * 10 * 34 * 8];  // 32640 B
  const int PP = 2 * 10 * 34 * 8;
  int tid = threadIdx.x;
  int n = blockIdx.x;
  int xcd = n & 7, m = n >> 3;
  int ty = xcd * 2 + (m & 1);
  int q0 = m >> 1;
  int b = q0 >> 2, xt = q0 & 3;
  int X0 = xt * 32, Y0 = ty * 8;
  const unsigned short* ip = h1s + (size_t)b * 262144;
  for (int g = tid; g < 680; g += 256) {  // pos(340) x ich(2) granule-groups
    int pos = g >> 1, ich = g & 1;
    int yy = pos / 34, xx = pos - yy * 34;
    int y = Y0 - 1 + yy, xg = X0 - 1 + xx;
    short8 v1 = {0, 0, 0, 0, 0, 0, 0, 0};
    short8 v2 = {0, 0, 0, 0, 0, 0, 0, 0};
    short8 v3 = {0, 0, 0, 0, 0, 0, 0, 0};
    if ((unsigned)y < 128u && (unsigned)xg < 128u) {
      const unsigned short* sp = ip + ((size_t)y * 128 + xg) * 16 + ich * 8;
      v1 = *(const short8*)(sp);
      v2 = *(const short8*)(sp + H1PL);
      v3 = *(const short8*)(sp + 2 * H1PL);
    }
    int si = ((ich * 10 + yy) * 34 + xx) * 8;
    *(short8*)(sA + si) = v1;
    *(short8*)(sA + PP + si) = v2;
    *(short8*)(sA + 2 * PP + si) = v3;
  }
  __syncthreads();

  int l = tid & 63, w = tid >> 6;
  int xl = l & 31, ich = l >> 5;
  f32x16 acc0[2], acc1[2];
#pragma unroll
  for (int s = 0; s < 2; ++s)
#pragma unroll
    for (int r = 0; r < 16; ++r) { acc0[s][r] = 0.f; acc1[s][r] = 0.f; }

#pragma unroll
  for (int t = 0; t < 9; ++t) {
    int dy = t / 3, dx = t % 3;
    int s = t & 1;
    const unsigned short* wb = wfrag + t * 512 + l * 8;
    short8 bf1 = *(const short8*)(wb);
    short8 bf2 = *(const short8*)(wb + 4608);
    short8 bf3 = *(const short8*)(wb + 9216);
    int g0 = ((ich * 10) + (2 * w + dy)) * 34 + xl + dx;
    const unsigned short* a0p = sA + g0 * 8;
    short8 a01 = *(const short8*)(a0p);
    short8 a02 = *(const short8*)(a0p + PP);
    short8 a03 = *(const short8*)(a0p + 2 * PP);
    const unsigned short* a1p = a0p + 34 * 8;
    short8 a11 = *(const short8*)(a1p);
    short8 a12 = *(const short8*)(a1p + PP);
    short8 a13 = *(const short8*)(a1p + 2 * PP);
    acc0[s] = MFMA32(a01, bf1, acc0[s], 0, 0, 0);
    acc0[s] = MFMA32(a01, bf2, acc0[s], 0, 0, 0);
    acc0[s] = MFMA32(a02, bf1, acc0[s], 0, 0, 0);
    acc0[s] = MFMA32(a02, bf2, acc0[s], 0, 0, 0);
    acc0[s] = MFMA32(a01, bf3, acc0[s], 0, 0, 0);
    acc0[s] = MFMA32(a03, bf1, acc0[s], 0, 0, 0);
    acc1[s] = MFMA32(a11, bf1, acc1[s], 0, 0, 0);
    acc1[s] = MFMA32(a11, bf2, acc1[s], 0, 0, 0);
    acc1[s] = MFMA32(a12, bf1, acc1[s], 0, 0, 0);
    acc1[s] = MFMA32(a12, bf2, acc1[s], 0, 0, 0);
    acc1[s] = MFMA32(a11, bf3, acc1[s], 0, 0, 0);
    acc1[s] = MFMA32(a13, bf1, acc1[s], 0, 0, 0);
  }

  float bv = bias[l & 31];
  int ypool = (Y0 >> 1) + w;
  float* op = h2 + (size_t)b * 131072 + (size_t)(l & 31) * 4096 + ypool * 64 + (X0 >> 1);
#pragma unroll
  for (int k = 0; k < 8; ++k) {
    float e0 = (acc0[0][2 * k] + acc0[1][2 * k]);
    float o0 = (acc0[0][2 * k + 1] + acc0[1][2 * k + 1]);
    float e1 = (acc1[0][2 * k] + acc1[1][2 * k]);
    float o1 = (acc1[0][2 * k + 1] + acc1[1][2 * k + 1]);
    float mm = fmaxf(fmaxf(e0, o0), fmaxf(e1, o1)) + bv;
    int row = ((2 * k) & 3) + 8 * ((2 * k) >> 2) + 4 * ich;
    op[row >> 1] = mm;
  }
}

// ---------------- Kernel C: VQ via exact-split bf16 MFMA (v4) ------------------
// r17: v3's direct register staging (no LDS transpose) + r14's arithmetic
// intensity: 64 tokens/wave (TQ=4) -> 24 MFMA per 3KB B-group, 512 blocks ->
// 192MB B-traffic (half of v3). The binding resource is L2-latency per MFMA,
// so tokens-per-wave beats wave count (r16 measured: TQ=2/16waves = 44.8us).
__global__ __launch_bounds__(256, 2) void k_vq(const float* __restrict__ h2,
                                               const unsigned short* __restrict__ cbs,
                                               const float* __restrict__ csqg,
                                               float* __restrict__ idxout,
                                               float* __restrict__ lossout) {
  __shared__ float sFsq[256];
  __shared__ float sBd[256];
  __shared__ int sBi[256];
  __shared__ float sred[4];
  int tid = threadIdx.x;
  int blk = blockIdx.x;
  int t0 = blk * 256;  // 16 blocks/batch: no batch straddle
  size_t abase = (size_t)(t0 >> 12) * 131072 + (t0 & 4095);

  int l = tid & 63, w = tid >> 6;
  int cl = l & 15, k0 = (l >> 4) * 8;

  // ---- direct staging: 4 tq x 8 ch per lane, split in-reg ----
  short8 af1[4], af2[4], af3[4];
  float fsq[4];
#pragma unroll
  for (int tq = 0; tq < 4; ++tq) {
    const float* src = h2 + abase + w * 64 + tq * 16 + cl;
    float fs = 0.f;
#pragma unroll
    for (int e = 0; e < 8; ++e) {
      float v = src[(size_t)(k0 + e) * 4096];
      fs = fmaf(v, v, fs);
      SPLIT3(v, u1, u2, u3)
      af1[tq][e] = (short)(u1 >> 16);
      af2[tq][e] = (short)(u2 >> 16);
      af3[tq][e] = (short)(u3 >> 16);
    }
    fsq[tq] = fs;
  }
#pragma unroll
  for (int tq = 0; tq < 4; ++tq) {  // total over the 4 k-groups of each token
    fsq[tq] += __shfl_xor(fsq[tq], 16, 64);
    fsq[tq] += __shfl_xor(fsq[tq], 32, 64);
  }
  if (l < 16) {
#pragma unroll
    for (int tq = 0; tq < 4; ++tq) sFsq[w * 64 + tq * 16 + l] = fsq[tq];
  }

  float bd[4][4];
  int bi[4][4];
#pragma unroll
  for (int a = 0; a < 4; ++a)
#pragma unroll
    for (int b = 0; b < 4; ++b) { bd[a][b] = 3.4e38f; bi[a][b] = 0; }

#define LOADB(S, CT)                                                           \
  {                                                                            \
    int col = (CT)*16 + cl;                                                    \
    b1##S = *(const short8*)(cbs + (0 * 512 + col) * 32 + k0);                 \
    b2##S = *(const short8*)(cbs + (1 * 512 + col) * 32 + k0);                 \
    b3##S = *(const short8*)(cbs + (2 * 512 + col) * 32 + k0);                 \
    cq##S = csqg[col];                                                         \
  }
#define COMPUTE(S, CT)                                                         \
  {                                                                            \
    _Pragma("unroll") for (int tq = 0; tq < 4; ++tq) {                         \
      f32x4 acc = {0.f, 0.f, 0.f, 0.f};                                        \
      acc = MFMA16(af1[tq], b1##S, acc, 0, 0, 0);                              \
      acc = MFMA16(af1[tq], b2##S, acc, 0, 0, 0);                              \
      acc = MFMA16(af2[tq], b1##S, acc, 0, 0, 0);                              \
      acc = MFMA16(af2[tq], b2##S, acc, 0, 0, 0);                              \
      acc = MFMA16(af1[tq], b3##S, acc, 0, 0, 0);                              \
      acc = MFMA16(af3[tq], b1##S, acc, 0, 0, 0);                              \
      _Pragma("unroll") for (int i = 0; i < 4; ++i) {                          \
        float d = fmaf(-2.f, acc[i], cq##S);                                   \
        if (d < bd[tq][i]) { bd[tq][i] = d; bi[tq][i] = (CT)*16 + cl; }        \
      }                                                                        \
    }                                                                          \
  }

  short8 b1A, b2A, b3A, b1B, b2B, b3B;
  float cqA, cqB;
  LOADB(A, 0)
  LOADB(B, 1)
#pragma unroll 1
  for (int ct = 0; ct < 32; ct += 2) {
    COMPUTE(A, ct)
    LOADB(A, (ct + 2) & 31)  // distance-2 prefetch; wrap: in-bounds, unused
    COMPUTE(B, ct + 1)
    LOADB(B, (ct + 3) & 31)
  }
#undef LOADB
#undef COMPUTE

  // ---- cross-lane argmin over 16 code-slices (lexicographic) ----
#pragma unroll
  for (int tq = 0; tq < 4; ++tq)
#pragma unroll
    for (int i = 0; i < 4; ++i)
#pragma unroll
      for (int m = 1; m < 16; m <<= 1) {
        float od = __shfl_xor(bd[tq][i], m, 64);
        int ob = __shfl_xor(bi[tq][i], m, 64);
        if (od < bd[tq][i] || (od == bd[tq][i] && ob < bi[tq][i])) {
          bd[tq][i] = od;
          bi[tq][i] = ob;
        }
      }
  if (cl == 0) {
#pragma unroll
    for (int tq = 0; tq < 4; ++tq)
#pragma unroll
      for (int i = 0; i < 4; ++i) {
        int tokl = w * 64 + tq * 16 + (l >> 4) * 4 + i;
        sBi[tokl] = bi[tq][i];
        sBd[tokl] = bd[tq][i];
      }
  }
  __syncthreads();

  idxout[t0 + tid] = (float)sBi[tid];
  float loss = sBd[tid] + sFsq[tid];  // ||q-f||^2 = csq - 2 f.c + ||f||^2
#pragma unroll
  for (int off = 32; off > 0; off >>= 1) loss += __shfl_down(loss, off, 64);
  if (l == 0) sred[w] = loss;
  __syncthreads();
  if (tid == 0)
    atomicAdd(lossout, ((sred[0] + sred[1]) + (sred[2] + sred[3])) * (1.0f / 4194304.0f));
}

// ---------------- Kernel D: up2 + conv (32->16) + gelu via split MFMA ----------
// (r13-verified: gather-direct A, 1 q-row/wave, interleaved d1o.)
__global__ __launch_bounds__(256) void k_dec1(const float* __restrict__ idxf,
                                              const unsigned short* __restrict__ cbs,
                                              const unsigned short* __restrict__ wfd1,
                                              const float* __restrict__ bias,
                                              float* __restrict__ o) {
  __shared__ int sIdx[204];  // 6 halo rows x 34 cols
  int tid = threadIdx.x;
  int b = blockIdx.y;
  int qx0 = (blockIdx.x & 1) * 32, qy0 = (blockIdx.x >> 1) * 4;
  const float* ib = idxf + (size_t)b * 4096;
  if (tid < 204) {
    int yy = tid / 34, xx = tid % 34;
    int y = qy0 - 1 + yy, x = qx0 - 1 + xx;
    sIdx[tid] = ((unsigned)y < 64u && (unsigned)x < 64u) ? (int)ib[y * 64 + x] : -1;
  }
  __syncthreads();

  int l = tid & 63, w = tid >> 6;  // wave w -> output q-row qy0+w
  int xl = l & 31, hi = l >> 5;
  f32x16 acc[2];  // [p2 = output row phase]
#pragma unroll
  for (int p2 = 0; p2 < 2; ++p2)
#pragma unroll
    for (int r = 0; r < 16; ++r) acc[p2][r] = 0.f;

#pragma unroll
  for (int cx = 0; cx < 3; ++cx) {
#pragma unroll
    for (int kh = 0; kh < 2; ++kh) {
      short8 Bf[4][3];  // q=(ry,pq) packed: 0:(0,0) 1:(1,0) 2:(1,1) 3:(2,1)
#pragma unroll
      for (int q = 0; q < 4; ++q) {
        int r3 = (q == 0) ? 0 : (q == 3) ? 2 : 1;
        int pq = (q >= 2) ? 1 : 0;
#pragma unroll
        for (int pt = 0; pt < 3; ++pt) {
          int slot = cx * 36 + r3 * 12 + kh * 6 + pq * 3 + pt;
          Bf[q][pt] = *(const short8*)(wfd1 + (size_t)slot * 512 + l * 8);
        }
      }
#pragma unroll
      for (int ry = 0; ry < 3; ++ry) {
        int idx = sIdx[(w + ry) * 34 + xl + cx];
        short8 a1 = {0, 0, 0, 0, 0, 0, 0, 0};
        short8 a2 = {0, 0, 0, 0, 0, 0, 0, 0};
        short8 a3 = {0, 0, 0, 0, 0, 0, 0, 0};
        if (idx >= 0) {
          const unsigned short* ap = cbs + (size_t)idx * 32 + kh * 16 + hi * 8;
          a1 = *(const short8*)(ap);
          a2 = *(const short8*)(ap + 16384);
          a3 = *(const short8*)(ap + 32768);
        }
#pragma unroll
        for (int p2 = 0; p2 < 2; ++p2) {
          if ((ry == 0 && p2 == 1) || (ry == 2 && p2 == 0)) continue;
          int q = ry + p2;
          f32x16 t = acc[p2];
          t = MFMA32(a1, Bf[q][0], t, 0, 0, 0);
          t = MFMA32(a1, Bf[q][1], t, 0, 0, 0);
          t = MFMA32(a2, Bf[q][0], t, 0, 0, 0);
          t = MFMA32(a2, Bf[q][1], t, 0, 0, 0);
          t = MFMA32(a1, Bf[q][2], t, 0, 0, 0);
          t = MFMA32(a3, Bf[q][0], t, 0, 0, 0);
          acc[p2] = t;
        }
      }
    }
  }

  float bv = bias[l & 15];
  int b2 = (l >> 4) & 1;
  int oc = l & 15;
  int qy = qy0 + w;
  float* ob = o + (size_t)b * 262144;
#pragma unroll
  for (int p2 = 0; p2 < 2; ++p2) {
    int Y = 2 * qy + p2;
#pragma unroll
    for (int reg = 0; reg < 16; ++reg) {
      int rowval = (reg & 3) + 8 * (reg >> 2) + 4 * hi;
      int X = qx0 * 2 + 2 * rowval + b2;
      ob[((size_t)Y * 128 + X) * 16 + oc] = GELU(acc[p2][reg] + bv);
    }
  }
}

// ---------------- Kernel E: up2 + conv (16->1) + clip, phase-folded ------------
// (r13-verified: interleaved input, position-major LDS [pos][17].)
__device__ __forceinline__ void d2_loadi3(float (&dst)[3][3], const float* t) {
#pragma unroll
  for (int dy = 0; dy < 3; ++dy)
#pragma unroll
    for (int dx = 0; dx < 3; ++dx) dst[dy][dx] = t[(dy * 18 + dx) * 17];
}
__global__ __launch_bounds__(256) void k_dec2(const float* __restrict__ d1,
                                              const float* __restrict__ fwd2,
                                              const float* __restrict__ bias,
                                              float* __restrict__ out) {
  __shared__ float st[18 * 18 * 17];  // [row][col][ic16 + pad]
  int tid = threadIdx.x;
  int b = blockIdx.y;
  int R0 = (blockIdx.x >> 3) * 16, C0 = (blockIdx.x & 7) * 16;
  const float* ip = d1 + (size_t)b * 262144;
  for (int i = tid; i < 1296; i += 256) {  // 324 pos x 4 ic-quads
    int pos = i >> 2, q = i & 3;
    int rr = pos / 18, cc = pos % 18;
    int r = R0 - 1 + rr, c = C0 - 1 + cc;
    float4 v = {0.f, 0.f, 0.f, 0.f};
    if ((unsigned)r < 128u && (unsigned)c < 128u)
      v = *(const float4*)(ip + ((size_t)r * 128 + c) * 16 + q * 4);
    float* dp = st + (rr * 18 + cc) * 17 + q * 4;
    dp[0] = v.x; dp[1] = v.y; dp[2] = v.z; dp[3] = v.w;
  }
  __syncthreads();
  int lane = tid & 63, wid = tid >> 6;
  int qy = wid >> 1, qx = wid & 1;
  int ty = qy * 8 + (lane >> 3), tx = qx * 8 + (lane & 7);
  float acc[4] = {0.f, 0.f, 0.f, 0.f};
  const float* tb = st + (ty * 18 + tx) * 17;
  float i3A[3][3], i3B[3][3];
  d2_loadi3(i3A, tb);
#pragma unroll 1
  for (int ic = 0; ic < 16; ic += 2) {
    d2_loadi3(i3B, tb + (ic + 1));
    {
      const float* wp = fwd2 + ic * 16;  // scalar loads
#pragma unroll
      for (int p = 0; p < 4; ++p) {
        int a = p >> 1, b2 = p & 1;
#pragma unroll
        for (int tp = 0; tp < 4; ++tp) {
          int dy = tp >> 1, dx = tp & 1;
          acc[p] = fmaf(i3A[a + dy][b2 + dx], wp[p * 4 + tp], acc[p]);
        }
      }
    }
    d2_loadi3(i3A, tb + ((ic + 2) & 15));  // wrap: harmless re-read
    {
      const float* wp = fwd2 + (ic + 1) * 16;
#pragma unroll
      for (int p = 0; p < 4; ++p) {
        int a = p >> 1, b2 = p & 1;
#pragma unroll
        for (int tp = 0; tp < 4; ++tp) {
          int dy = tp >> 1, dx = tp & 1;
          acc[p] = fmaf(i3B[a + dy][b2 + dx], wp[p * 4 + tp], acc[p]);
        }
      }
    }
  }
  float bv = bias[0];
  int Y = 2 * (R0 + ty), X = 2 * (C0 + tx);
  float* op = out + (size_t)b * 65536 + Y * 256 + X;
  float2 r0v, r1v;
  r0v.x = fminf(1.0f, fmaxf(-1.0f, acc[0] + bv));
  r0v.y = fminf(1.0f, fmaxf(-1.0f, acc[1] + bv));
  r1v.x = fminf(1.0f, fmaxf(-1.0f, acc[2] + bv));
  r1v.y = fminf(1.0f, fmaxf(-1.0f, acc[3] + bv));
  *(float2*)op = r0v;
  *(float2*)(op + 256) = r1v;
}

extern "C" void kernel_launch(void* const* d_in, const int* in_sizes, int n_in,
                              void* d_out, int out_size, void* d_ws, size_t ws_size,
                              hipStream_t stream) {
  const float* x   = (const float*)d_in[0];
  const float* e1w = (const float*)d_in[1];
  const float* e1b = (const float*)d_in[2];
  const float* e2w = (const float*)d_in[3];
  const float* e2b = (const float*)d_in[4];
  const float* cb  = (const float*)d_in[5];
  const float* d1w = (const float*)d_in[6];
  const float* d1b = (const float*)d_in[7];
  const float* d2w = (const float*)d_in[8];
  const float* d2b = (const float*)d_in[9];

  float* out = (float*)d_out;
  float* y       = out;                       // [32,1,256,256] = 2097152
  float* idxout  = out + 2097152;             // [32,64,64]     = 131072 (as float)
  float* lossout = out + 2097152 + 131072;    // scalar

  // Workspace layout:
  //  h1s: 3 bf16 planes, 3 x 8388608 shorts = 12582912 floats  [0, 12582912)
  //  h2 : fp32 [32][32][64][64]                                [12582912, 16777216)
  //  fwd2: 256 floats                                          [16777216, ...)
  //  d1o: fp32 [32][128][128][16], reuses h1s region (dead after enc2)
  float* ws = (float*)d_ws;
  unsigned short* h1s = (unsigned short*)ws;
  float* h2      = ws + 12582912;
  float* fwd2    = ws + 16777216;
  float* d1o     = ws;  // 8388608 floats, fits in h1s region

  // Scratch in the y-region of out (written by k_fold, consumed before k_dec2
  // overwrites all of y): cbs 24576f, csqg 512f, wfrag 6912f, wfd1 27648f.
  unsigned short* cbs = (unsigned short*)out;              // 49152 bf16
  float* csqg = out + 24576;                               // 512
  unsigned short* wfrag = (unsigned short*)(out + 25088);  // 13824 bf16
  unsigned short* wfd1 = (unsigned short*)(out + 32000);   // 55296 bf16

  k_fold<<<dim3(337), 256, 0, stream>>>(e2w, d1w, d2w, cb, fwd2, cbs, csqg, wfrag, wfd1, lossout);
  k_enc1<<<dim3(2048), 256, 0, stream>>>(x, e1w, e1b, h1s);
  k_enc2<<<dim3(2048), 256, 0, stream>>>(h1s, wfrag, e2b, h2);
  k_vq<<<dim3(512), 256, 0, stream>>>(h2, cbs, csqg, idxout, lossout);
  k_dec1<<<dim3(32, 32), 256, 0, stream>>>(idxout, cbs, wfd1, d1b, d1o);
  k_dec2<<<dim3(64, 32), 256, 0, stream>>>(d1o, fwd2, d2b, y);
}

// Round 18
// 204.328 us; speedup vs baseline: 1.0716x; 1.0326x over previous
//
#include <hip/hip_runtime.h>
#include <math.h>

#define GELU(v) (0.5f * (v) * (1.0f + erff((v)*0.70710678118654752440f)))

typedef __attribute__((ext_vector_type(8))) short short8;
typedef __attribute__((ext_vector_type(4))) float f32x4;
typedef __attribute__((ext_vector_type(16))) float f32x16;
#define MFMA16 __builtin_amdgcn_mfma_f32_16x16x32_bf16
#define MFMA32 __builtin_amdgcn_mfma_f32_32x32x16_bf16

// Exact 3-way bf16 split of fp32 (24 = 3x8 mantissa bits, truncation):
// v == p1 + p2 + p3 exactly (each pi representable in bf16).
#define SPLIT3(V, U1, U2, U3)                                                  \
  unsigned U1 = __float_as_uint(V) & 0xFFFF0000u;                              \
  float _r1 = (V)-__uint_as_float(U1);                                         \
  unsigned U2 = __float_as_uint(_r1) & 0xFFFF0000u;                            \
  float _r2 = _r1 - __uint_as_float(U2);                                       \
  unsigned U3 = __float_as_uint(_r2) & 0xFFFF0000u;

#define H1PL 8388608  // h1s plane stride in shorts: 32b x 128 x 128 x 16

// ---------------- Kernel A+setup: conv1 fused with weight-fold -----------------
// Blocks [0,2048): enc1 (r14 pre-split output, r12 XCD-slab mapping).
// Blocks [2048,2385): the old k_fold body (independent work: reads weights/cb,
// writes fwd2/cbs/csqg/wfrag/wfd1/lossout) — saves one dispatch + gap.
__global__ __launch_bounds__(256) void k_enc1f(const float* __restrict__ x,
                                               const float* __restrict__ e1w,
                                               const float* __restrict__ e1b,
                                               unsigned short* __restrict__ h1s,
                                               const float* __restrict__ e2w,
                                               const float* __restrict__ d1w,
                                               const float* __restrict__ d2w,
                                               const float* __restrict__ cb,
                                               float* __restrict__ fwd2,
                                               unsigned short* __restrict__ cbs,
                                               float* __restrict__ csqg,
                                               unsigned short* __restrict__ wfrag,
                                               unsigned short* __restrict__ wfd1,
                                               float* __restrict__ lossout) {
  int n = blockIdx.x;
  if (n >= 2048) {
    // ---------------- fold branch ----------------
    int i = (n - 2048) * 256 + threadIdx.x;
    if (i == 0) lossout[0] = 0.f;  // k_vq accumulates atomically
    if (i < 256) {
      int j = i;
      int pt = j & 15, ic = j >> 4;
      int a = pt >> 3, b2 = (pt >> 2) & 1, dy = (pt >> 1) & 1, dx = pt & 1;
      const float* wsrc = d2w + ic * 9;
      float s = 0.f;
      for (int ky = 0; ky < 3; ++ky) {
        int rm = (a == 0) ? (ky == 0 ? 0 : 1) : (ky == 2 ? 1 : 0);
        if (rm != dy) continue;
        for (int kx = 0; kx < 3; ++kx) {
          int cm = (b2 == 0) ? (kx == 0 ? 0 : 1) : (kx == 2 ? 1 : 0);
          if (cm == dx) s += wsrc[ky * 3 + kx];
        }
      }
      fwd2[j] = s;
    } else if (i < 16640) {
      int j = i - 256;  // [0, 16384): code = j>>5, ch = j&31
      float v = cb[j];
      SPLIT3(v, u1, u2, u3)
      cbs[j] = (unsigned short)(u1 >> 16);
      cbs[16384 + j] = (unsigned short)(u2 >> 16);
      cbs[32768 + j] = (unsigned short)(u3 >> 16);
    } else if (i < 17152) {
      int c = i - 16640;
      const float* row = cb + (size_t)c * 32;
      float s = 0.f;
#pragma unroll
      for (int d = 0; d < 32; ++d) s = fmaf(row[d], row[d], s);
      csqg[c] = s;
    } else if (i < 30976) {
      int j = i - 17152;  // [0, 13824)
      int p = j / 4608, rem = j - p * 4608;
      int t = rem >> 9, l2 = (rem >> 3) & 63, jj = rem & 7;
      float v = e2w[((l2 & 31) * 16 + ((l2 >> 5) * 8 + jj)) * 9 + t];
      SPLIT3(v, u1, u2, u3)
      unsigned short r = (p == 0)   ? (unsigned short)(u1 >> 16)
                         : (p == 1) ? (unsigned short)(u2 >> 16)
                                    : (unsigned short)(u3 >> 16);
      wfrag[j] = r;
    } else if (i < 86272) {
      int j = i - 30976;  // [0, 55296)
      int slot = j >> 9, l2 = (j >> 3) & 63, jj = j & 7;
      int cx = slot / 36, rem = slot % 36;
      int r3 = rem / 12, rem2 = rem % 12;
      int kh = rem2 / 6, rem3 = rem2 % 6;
      int pp = rem3 / 3, part = rem3 % 3;
      int c = l2 & 31, hi = l2 >> 5;
      int oc = c & 15, b2 = c >> 4;
      int ic = kh * 16 + hi * 8 + jj;
      int dy = r3 - pp, dx = cx - b2;
      float s = 0.f;
      if ((unsigned)dy < 2u && (unsigned)dx < 2u) {
        const float* wsrc = d1w + (oc * 32 + ic) * 9;
        for (int ky = 0; ky < 3; ++ky) {
          int rm = (pp == 0) ? (ky == 0 ? 0 : 1) : (ky == 2 ? 1 : 0);
          if (rm != dy) continue;
          for (int kx = 0; kx < 3; ++kx) {
            int cm = (b2 == 0) ? (kx == 0 ? 0 : 1) : (kx == 2 ? 1 : 0);
            if (cm == dx) s += wsrc[ky * 3 + kx];
          }
        }
      }
      SPLIT3(s, u1, u2, u3)
      unsigned short r = (part == 0)   ? (unsigned short)(u1 >> 16)
                         : (part == 1) ? (unsigned short)(u2 >> 16)
                                       : (unsigned short)(u3 >> 16);
      wfd1[j] = r;
    }
    return;
  }
  // ---------------- enc1 branch ----------------
  int ysl = n & 7, m = n >> 3;
  int b = m & 31, k = m >> 5;
  int yy = ysl * 16 + k * 2 + (threadIdx.x >> 7);
  int xx = threadIdx.x & 127;
  const float* xp = x + (size_t)b * 65536;
  int r0 = 2 * yy - 1, c0 = 2 * xx - 1;
  float in[4][4];
#pragma unroll
  for (int i = 0; i < 4; ++i) {
    int r = r0 + i;
    bool rv = (unsigned)r < 256u;
#pragma unroll
    for (int j = 0; j < 4; ++j) {
      int c = c0 + j;
      in[i][j] = (rv && (unsigned)c < 256u) ? xp[r * 256 + c] : 0.0f;
    }
  }
  short8 p1[2], p2[2], p3[2];
#pragma unroll
  for (int oc = 0; oc < 16; ++oc) {
    const float* wp = e1w + oc * 9;  // uniform -> s_load
    float s00 = 0.f, s01 = 0.f, s10 = 0.f, s11 = 0.f;
#pragma unroll
    for (int ky = 0; ky < 3; ++ky)
#pragma unroll
      for (int kx = 0; kx < 3; ++kx) {
        float wv = wp[ky * 3 + kx];
        s00 = fmaf(in[ky][kx], wv, s00);
        s01 = fmaf(in[ky][kx + 1], wv, s01);
        s10 = fmaf(in[ky + 1][kx], wv, s10);
        s11 = fmaf(in[ky + 1][kx + 1], wv, s11);
      }
    float mm = fmaxf(fmaxf(s00, s01), fmaxf(s10, s11)) + e1b[oc];
    float g = GELU(mm);
    SPLIT3(g, u1, u2, u3)
    p1[oc >> 3][oc & 7] = (short)(u1 >> 16);
    p2[oc >> 3][oc & 7] = (short)(u2 >> 16);
    p3[oc >> 3][oc & 7] = (short)(u3 >> 16);
  }
  unsigned short* op = h1s + (size_t)b * 262144 + ((size_t)yy * 128 + xx) * 16;
  *(short8*)(op) = p1[0];
  *(short8*)(op + 8) = p1[1];
  *(short8*)(op + H1PL) = p2[0];
  *(short8*)(op + H1PL + 8) = p2[1];
  *(short8*)(op + 2 * H1PL) = p3[0];
  *(short8*)(op + 2 * H1PL + 8) = p3[1];
}

// ---------------- Kernel B: conv2 (16->32) + maxpool2 via split MFMA -----------
// (r14: pure 16B-copy staging from pre-split h1s; r12 XCD-matched grid.)
__global__ __launch_bounds__(256) void k_enc2(const unsigned short* __restrict__ h1s,
                                              const unsigned short* __restrict__ wfrag,
                                              const float* __restrict__ bias,
                                              float* __restrict__ h2) {
  __shared__ __align__(16) unsigned short sA[3 * 2 * 10 * 34 * 8];  // 32640 B
  const int PP = 2 * 10 * 34 * 8;
  int tid = threadIdx.x;
  int n = blockIdx.x;
  int xcd = n & 7, m = n >> 3;
  int ty = xcd * 2 + (m & 1);
  int q0 = m >> 1;
  int b = q0 >> 2, xt = q0 & 3;
  int X0 = xt * 32, Y0 = ty * 8;
  const unsigned short* ip = h1s + (size_t)b * 262144;
  for (int g = tid; g < 680; g += 256) {  // pos(340) x ich(2) granule-groups
    int pos = g >> 1, ich = g & 1;
    int yy = pos / 34, xx = pos - yy * 34;
    int y = Y0 - 1 + yy, xg = X0 - 1 + xx;
    short8 v1 = {0, 0, 0, 0, 0, 0, 0, 0};
    short8 v2 = {0, 0, 0, 0, 0, 0, 0, 0};
    short8 v3 = {0, 0, 0, 0, 0, 0, 0, 0};
    if ((unsigned)y < 128u && (unsigned)xg < 128u) {
      const unsigned short* sp = ip + ((size_t)y * 128 + xg) * 16 + ich * 8;
      v1 = *(const short8*)(sp);
      v2 = *(const short8*)(sp + H1PL);
      v3 = *(const short8*)(sp + 2 * H1PL);
    }
    int si = ((ich * 10 + yy) * 34 + xx) * 8;
    *(short8*)(sA + si) = v1;
    *(short8*)(sA + PP + si) = v2;
    *(short8*)(sA + 2 * PP + si) = v3;
  }
  __syncthreads();

  int l = tid & 63, w = tid >> 6;
  int xl = l & 31, ich = l >> 5;
  f32x16 acc0[2], acc1[2];
#pragma unroll
  for (int s = 0; s < 2; ++s)
#pragma unroll
    for (int r = 0; r < 16; ++r) { acc0[s][r] = 0.f; acc1[s][r] = 0.f; }

#pragma unroll
  for (int t = 0; t < 9; ++t) {
    int dy = t / 3, dx = t % 3;
    int s = t & 1;
    const unsigned short* wb = wfrag + t * 512 + l * 8;
    short8 bf1 = *(const short8*)(wb);
    short8 bf2 = *(const short8*)(wb + 4608);
    short8 bf3 = *(const short8*)(wb + 9216);
    int g0 = ((ich * 10) + (2 * w + dy)) * 34 + xl + dx;
    const unsigned short* a0p = sA + g0 * 8;
    short8 a01 = *(const short8*)(a0p);
    short8 a02 = *(const short8*)(a0p + PP);
    short8 a03 = *(const short8*)(a0p + 2 * PP);
    const unsigned short* a1p = a0p + 34 * 8;
    short8 a11 = *(const short8*)(a1p);
    short8 a12 = *(const short8*)(a1p + PP);
    short8 a13 = *(const short8*)(a1p + 2 * PP);
    acc0[s] = MFMA32(a01, bf1, acc0[s], 0, 0, 0);
    acc0[s] = MFMA32(a01, bf2, acc0[s], 0, 0, 0);
    acc0[s] = MFMA32(a02, bf1, acc0[s], 0, 0, 0);
    acc0[s] = MFMA32(a02, bf2, acc0[s], 0, 0, 0);
    acc0[s] = MFMA32(a01, bf3, acc0[s], 0, 0, 0);
    acc0[s] = MFMA32(a03, bf1, acc0[s], 0, 0, 0);
    acc1[s] = MFMA32(a11, bf1, acc1[s], 0, 0, 0);
    acc1[s] = MFMA32(a11, bf2, acc1[s], 0, 0, 0);
    acc1[s] = MFMA32(a12, bf1, acc1[s], 0, 0, 0);
    acc1[s] = MFMA32(a12, bf2, acc1[s], 0, 0, 0);
    acc1[s] = MFMA32(a11, bf3, acc1[s], 0, 0, 0);
    acc1[s] = MFMA32(a13, bf1, acc1[s], 0, 0, 0);
  }

  float bv = bias[l & 31];
  int ypool = (Y0 >> 1) + w;
  float* op = h2 + (size_t)b * 131072 + (size_t)(l & 31) * 4096 + ypool * 64 + (X0 >> 1);
#pragma unroll
  for (int k = 0; k < 8; ++k) {
    float e0 = (acc0[0][2 * k] + acc0[1][2 * k]);
    float o0 = (acc0[0][2 * k + 1] + acc0[1][2 * k + 1]);
    float e1 = (acc1[0][2 * k] + acc1[1][2 * k]);
    float o1 = (acc1[0][2 * k + 1] + acc1[1][2 * k + 1]);
    float mm = fmaxf(fmaxf(e0, o0), fmaxf(e1, o1)) + bv;
    int row = ((2 * k) & 3) + 8 * ((2 * k) >> 2) + 4 * ich;
    op[row >> 1] = mm;
  }
}

// ---------------- Kernel C: VQ via exact-split bf16 MFMA (v4, r17-verified) ----
__global__ __launch_bounds__(256, 2) void k_vq(const float* __restrict__ h2,
                                               const unsigned short* __restrict__ cbs,
                                               const float* __restrict__ csqg,
                                               float* __restrict__ idxout,
                                               float* __restrict__ lossout) {
  __shared__ float sFsq[256];
  __shared__ float sBd[256];
  __shared__ int sBi[256];
  __shared__ float sred[4];
  int tid = threadIdx.x;
  int blk = blockIdx.x;
  int t0 = blk * 256;  // 16 blocks/batch: no batch straddle
  size_t abase = (size_t)(t0 >> 12) * 131072 + (t0 & 4095);

  int l = tid & 63, w = tid >> 6;
  int cl = l & 15, k0 = (l >> 4) * 8;

  // ---- direct staging: 4 tq x 8 ch per lane, split in-reg ----
  short8 af1[4], af2[4], af3[4];
  float fsq[4];
#pragma unroll
  for (int tq = 0; tq < 4; ++tq) {
    const float* src = h2 + abase + w * 64 + tq * 16 + cl;
    float fs = 0.f;
#pragma unroll
    for (int e = 0; e < 8; ++e) {
      float v = src[(size_t)(k0 + e) * 4096];
      fs = fmaf(v, v, fs);
      SPLIT3(v, u1, u2, u3)
      af1[tq][e] = (short)(u1 >> 16);
      af2[tq][e] = (short)(u2 >> 16);
      af3[tq][e] = (short)(u3 >> 16);
    }
    fsq[tq] = fs;
  }
#pragma unroll
  for (int tq = 0; tq < 4; ++tq) {  // total over the 4 k-groups of each token
    fsq[tq] += __shfl_xor(fsq[tq], 16, 64);
    fsq[tq] += __shfl_xor(fsq[tq], 32, 64);
  }
  if (l < 16) {
#pragma unroll
    for (int tq = 0; tq < 4; ++tq) sFsq[w * 64 + tq * 16 + l] = fsq[tq];
  }

  float bd[4][4];
  int bi[4][4];
#pragma unroll
  for (int a = 0; a < 4; ++a)
#pragma unroll
    for (int b = 0; b < 4; ++b) { bd[a][b] = 3.4e38f; bi[a][b] = 0; }

#define LOADB(S, CT)                                                           \
  {                                                                            \
    int col = (CT)*16 + cl;                                                    \
    b1##S = *(const short8*)(cbs + (0 * 512 + col) * 32 + k0);                 \
    b2##S = *(const short8*)(cbs + (1 * 512 + col) * 32 + k0);                 \
    b3##S = *(const short8*)(cbs + (2 * 512 + col) * 32 + k0);                 \
    cq##S = csqg[col];                                                         \
  }
#define COMPUTE(S, CT)                                                         \
  {                                                                            \
    _Pragma("unroll") for (int tq = 0; tq < 4; ++tq) {                         \
      f32x4 acc = {0.f, 0.f, 0.f, 0.f};                                        \
      acc = MFMA16(af1[tq], b1##S, acc, 0, 0, 0);                              \
      acc = MFMA16(af1[tq], b2##S, acc, 0, 0, 0);                              \
      acc = MFMA16(af2[tq], b1##S, acc, 0, 0, 0);                              \
      acc = MFMA16(af2[tq], b2##S, acc, 0, 0, 0);                              \
      acc = MFMA16(af1[tq], b3##S, acc, 0, 0, 0);                              \
      acc = MFMA16(af3[tq], b1##S, acc, 0, 0, 0);                              \
      _Pragma("unroll") for (int i = 0; i < 4; ++i) {                          \
        float d = fmaf(-2.f, acc[i], cq##S);                                   \
        if (d < bd[tq][i]) { bd[tq][i] = d; bi[tq][i] = (CT)*16 + cl; }        \
      }                                                                        \
    }                                                                          \
  }

  short8 b1A, b2A, b3A, b1B, b2B, b3B;
  float cqA, cqB;
  LOADB(A, 0)
  LOADB(B, 1)
#pragma unroll 1
  for (int ct = 0; ct < 32; ct += 2) {
    COMPUTE(A, ct)
    LOADB(A, (ct + 2) & 31)  // distance-2 prefetch; wrap: in-bounds, unused
    COMPUTE(B, ct + 1)
    LOADB(B, (ct + 3) & 31)
  }
#undef LOADB
#undef COMPUTE

  // ---- cross-lane argmin over 16 code-slices (lexicographic) ----
#pragma unroll
  for (int tq = 0; tq < 4; ++tq)
#pragma unroll
    for (int i = 0; i < 4; ++i)
#pragma unroll
      for (int m = 1; m < 16; m <<= 1) {
        float od = __shfl_xor(bd[tq][i], m, 64);
        int ob = __shfl_xor(bi[tq][i], m, 64);
        if (od < bd[tq][i] || (od == bd[tq][i] && ob < bi[tq][i])) {
          bd[tq][i] = od;
          bi[tq][i] = ob;
        }
      }
  if (cl == 0) {
#pragma unroll
    for (int tq = 0; tq < 4; ++tq)
#pragma unroll
      for (int i = 0; i < 4; ++i) {
        int tokl = w * 64 + tq * 16 + (l >> 4) * 4 + i;
        sBi[tokl] = bi[tq][i];
        sBd[tokl] = bd[tq][i];
      }
  }
  __syncthreads();

  idxout[t0 + tid] = (float)sBi[tid];
  float loss = sBd[tid] + sFsq[tid];  // ||q-f||^2 = csq - 2 f.c + ||f||^2
#pragma unroll
  for (int off = 32; off > 0; off >>= 1) loss += __shfl_down(loss, off, 64);
  if (l == 0) sred[w] = loss;
  __syncthreads();
  if (tid == 0)
    atomicAdd(lossout, ((sred[0] + sred[1]) + (sred[2] + sred[3])) * (1.0f / 4194304.0f));
}

// ---------------- Kernel D: up2 + conv (32->16) + gelu via split MFMA ----------
// (r13-verified: gather-direct A, 1 q-row/wave, interleaved d1o.)
__global__ __launch_bounds__(256) void k_dec1(const float* __restrict__ idxf,
                                              const unsigned short* __restrict__ cbs,
                                              const unsigned short* __restrict__ wfd1,
                                              const float* __restrict__ bias,
                                              float* __restrict__ o) {
  __shared__ int sIdx[204];  // 6 halo rows x 34 cols
  int tid = threadIdx.x;
  int b = blockIdx.y;
  int qx0 = (blockIdx.x & 1) * 32, qy0 = (blockIdx.x >> 1) * 4;
  const float* ib = idxf + (size_t)b * 4096;
  if (tid < 204) {
    int yy = tid / 34, xx = tid % 34;
    int y = qy0 - 1 + yy, x = qx0 - 1 + xx;
    sIdx[tid] = ((unsigned)y < 64u && (unsigned)x < 64u) ? (int)ib[y * 64 + x] : -1;
  }
  __syncthreads();

  int l = tid & 63, w = tid >> 6;  // wave w -> output q-row qy0+w
  int xl = l & 31, hi = l >> 5;
  f32x16 acc[2];  // [p2 = output row phase]
#pragma unroll
  for (int p2 = 0; p2 < 2; ++p2)
#pragma unroll
    for (int r = 0; r < 16; ++r) acc[p2][r] = 0.f;

#pragma unroll
  for (int cx = 0; cx < 3; ++cx) {
#pragma unroll
    for (int kh = 0; kh < 2; ++kh) {
      short8 Bf[4][3];  // q=(ry,pq) packed: 0:(0,0) 1:(1,0) 2:(1,1) 3:(2,1)
#pragma unroll
      for (int q = 0; q < 4; ++q) {
        int r3 = (q == 0) ? 0 : (q == 3) ? 2 : 1;
        int pq = (q >= 2) ? 1 : 0;
#pragma unroll
        for (int pt = 0; pt < 3; ++pt) {
          int slot = cx * 36 + r3 * 12 + kh * 6 + pq * 3 + pt;
          Bf[q][pt] = *(const short8*)(wfd1 + (size_t)slot * 512 + l * 8);
        }
      }
#pragma unroll
      for (int ry = 0; ry < 3; ++ry) {
        int idx = sIdx[(w + ry) * 34 + xl + cx];
        short8 a1 = {0, 0, 0, 0, 0, 0, 0, 0};
        short8 a2 = {0, 0, 0, 0, 0, 0, 0, 0};
        short8 a3 = {0, 0, 0, 0, 0, 0, 0, 0};
        if (idx >= 0) {
          const unsigned short* ap = cbs + (size_t)idx * 32 + kh * 16 + hi * 8;
          a1 = *(const short8*)(ap);
          a2 = *(const short8*)(ap + 16384);
          a3 = *(const short8*)(ap + 32768);
        }
#pragma unroll
        for (int p2 = 0; p2 < 2; ++p2) {
          if ((ry == 0 && p2 == 1) || (ry == 2 && p2 == 0)) continue;
          int q = ry + p2;
          f32x16 t = acc[p2];
          t = MFMA32(a1, Bf[q][0], t, 0, 0, 0);
          t = MFMA32(a1, Bf[q][1], t, 0, 0, 0);
          t = MFMA32(a2, Bf[q][0], t, 0, 0, 0);
          t = MFMA32(a2, Bf[q][1], t, 0, 0, 0);
          t = MFMA32(a1, Bf[q][2], t, 0, 0, 0);
          t = MFMA32(a3, Bf[q][0], t, 0, 0, 0);
          acc[p2] = t;
        }
      }
    }
  }

  float bv = bias[l & 15];
  int b2 = (l >> 4) & 1;
  int oc = l & 15;
  int qy = qy0 + w;
  float* ob = o + (size_t)b * 262144;
#pragma unroll
  for (int p2 = 0; p2 < 2; ++p2) {
    int Y = 2 * qy + p2;
#pragma unroll
    for (int reg = 0; reg < 16; ++reg) {
      int rowval = (reg & 3) + 8 * (reg >> 2) + 4 * hi;
      int X = qx0 * 2 + 2 * rowval + b2;
      ob[((size_t)Y * 128 + X) * 16 + oc] = GELU(acc[p2][reg] + bv);
    }
  }
}

// ---------------- Kernel E: up2 + conv (16->1) + clip, phase-folded ------------
// (r13-verified: interleaved input, position-major LDS [pos][17].)
__device__ __forceinline__ void d2_loadi3(float (&dst)[3][3], const float* t) {
#pragma unroll
  for (int dy = 0; dy < 3; ++dy)
#pragma unroll
    for (int dx = 0; dx < 3; ++dx) dst[dy][dx] = t[(dy * 18 + dx) * 17];
}
__global__ __launch_bounds__(256) void k_dec2(const float* __restrict__ d1,
                                              const float* __restrict__ fwd2,
                                              const float* __restrict__ bias,
                                              float* __restrict__ out) {
  __shared__ float st[18 * 18 * 17];  // [row][col][ic16 + pad]
  int tid = threadIdx.x;
  int b = blockIdx.y;
  int R0 = (blockIdx.x >> 3) * 16, C0 = (blockIdx.x & 7) * 16;
  const float* ip = d1 + (size_t)b * 262144;
  for (int i = tid; i < 1296; i += 256) {  // 324 pos x 4 ic-quads
    int pos = i >> 2, q = i & 3;
    int rr = pos / 18, cc = pos % 18;
    int r = R0 - 1 + rr, c = C0 - 1 + cc;
    float4 v = {0.f, 0.f, 0.f, 0.f};
    if ((unsigned)r < 128u && (unsigned)c < 128u)
      v = *(const float4*)(ip + ((size_t)r * 128 + c) * 16 + q * 4);
    float* dp = st + (rr * 18 + cc) * 17 + q * 4;
    dp[0] = v.x; dp[1] = v.y; dp[2] = v.z; dp[3] = v.w;
  }
  __syncthreads();
  int lane = tid & 63, wid = tid >> 6;
  int qy = wid >> 1, qx = wid & 1;
  int ty = qy * 8 + (lane >> 3), tx = qx * 8 + (lane & 7);
  float acc[4] = {0.f, 0.f, 0.f, 0.f};
  const float* tb = st + (ty * 18 + tx) * 17;
  float i3A[3][3], i3B[3][3];
  d2_loadi3(i3A, tb);
#pragma unroll 1
  for (int ic = 0; ic < 16; ic += 2) {
    d2_loadi3(i3B, tb + (ic + 1));
    {
      const float* wp = fwd2 + ic * 16;  // scalar loads
#pragma unroll
      for (int p = 0; p < 4; ++p) {
        int a = p >> 1, b2 = p & 1;
#pragma unroll
        for (int tp = 0; tp < 4; ++tp) {
          int dy = tp >> 1, dx = tp & 1;
          acc[p] = fmaf(i3A[a + dy][b2 + dx], wp[p * 4 + tp], acc[p]);
        }
      }
    }
    d2_loadi3(i3A, tb + ((ic + 2) & 15));  // wrap: harmless re-read
    {
      const float* wp = fwd2 + (ic + 1) * 16;
#pragma unroll
      for (int p = 0; p < 4; ++p) {
        int a = p >> 1, b2 = p & 1;
#pragma unroll
        for (int tp = 0; tp < 4; ++tp) {
          int dy = tp >> 1, dx = tp & 1;
          acc[p] = fmaf(i3B[a + dy][b2 + dx], wp[p * 4 + tp], acc[p]);
        }
      }
    }
  }
  float bv = bias[0];
  int Y = 2 * (R0 + ty), X = 2 * (C0 + tx);
  float* op = out + (size_t)b * 65536 + Y * 256 + X;
  float2 r0v, r1v;
  r0v.x = fminf(1.0f, fmaxf(-1.0f, acc[0] + bv));
  r0v.y = fminf(1.0f, fmaxf(-1.0f, acc[1] + bv));
  r1v.x = fminf(1.0f, fmaxf(-1.0f, acc[2] + bv));
  r1v.y = fminf(1.0f, fmaxf(-1.0f, acc[3] + bv));
  *(float2*)op = r0v;
  *(float2*)(op + 256) = r1v;
}

extern "C" void kernel_launch(void* const* d_in, const int* in_sizes, int n_in,
                              void* d_out, int out_size, void* d_ws, size_t ws_size,
                              hipStream_t stream) {
  const float* x   = (const float*)d_in[0];
  const float* e1w = (const float*)d_in[1];
  const float* e1b = (const float*)d_in[2];
  const float* e2w = (const float*)d_in[3];
  const float* e2b = (const float*)d_in[4];
  const float* cb  = (const float*)d_in[5];
  const float* d1w = (const float*)d_in[6];
  const float* d1b = (const float*)d_in[7];
  const float* d2w = (const float*)d_in[8];
  const float* d2b = (const float*)d_in[9];

  float* out = (float*)d_out;
  float* y       = out;                       // [32,1,256,256] = 2097152
  float* idxout  = out + 2097152;             // [32,64,64]     = 131072 (as float)
  float* lossout = out + 2097152 + 131072;    // scalar

  // Workspace layout:
  //  h1s: 3 bf16 planes, 3 x 8388608 shorts = 12582912 floats  [0, 12582912)
  //  h2 : fp32 [32][32][64][64]                                [12582912, 16777216)
  //  fwd2: 256 floats                                          [16777216, ...)
  //  d1o: fp32 [32][128][128][16], reuses h1s region (dead after enc2)
  float* ws = (float*)d_ws;
  unsigned short* h1s = (unsigned short*)ws;
  float* h2      = ws + 12582912;
  float* fwd2    = ws + 16777216;
  float* d1o     = ws;  // 8388608 floats, fits in h1s region

  // Scratch in the y-region of out (written by the fold branch, consumed before
  // k_dec2 overwrites all of y): cbs 24576f, csqg 512f, wfrag 6912f, wfd1 27648f.
  unsigned short* cbs = (unsigned short*)out;              // 49152 bf16
  float* csqg = out + 24576;                               // 512
  unsigned short* wfrag = (unsigned short*)(out + 25088);  // 13824 bf16
  unsigned short* wfd1 = (unsigned short*)(out + 32000);   // 55296 bf16

  k_enc1f<<<dim3(2385), 256, 0, stream>>>(x, e1w, e1b, h1s, e2w, d1w, d2w, cb,
                                          fwd2, cbs, csqg, wfrag, wfd1, lossout);
  k_enc2<<<dim3(2048), 256, 0, stream>>>(h1s, wfrag, e2b, h2);
  k_vq<<<dim3(512), 256, 0, stream>>>(h2, cbs, csqg, idxout, lossout);
  k_dec1<<<dim3(32, 32), 256, 0, stream>>>(idxout, cbs, wfd1, d1b, d1o);
  k_dec2<<<dim3(64, 32), 256, 0, stream>>>(d1o, fwd2, d2b, y);
}

// Round 19
// 203.243 us; speedup vs baseline: 1.0773x; 1.0053x over previous
//
#include <hip/hip_runtime.h>
#include <math.h>

#define GELU(v) (0.5f * (v) * (1.0f + erff((v)*0.70710678118654752440f)))

typedef __attribute__((ext_vector_type(8))) short short8;
typedef __attribute__((ext_vector_type(4))) float f32x4;
typedef __attribute__((ext_vector_type(16))) float f32x16;
#define MFMA16 __builtin_amdgcn_mfma_f32_16x16x32_bf16
#define MFMA32 __builtin_amdgcn_mfma_f32_32x32x16_bf16

// Exact 3-way bf16 split of fp32 (24 = 3x8 mantissa bits, truncation):
// v == p1 + p2 + p3 exactly (each pi representable in bf16).
#define SPLIT3(V, U1, U2, U3)                                                  \
  unsigned U1 = __float_as_uint(V) & 0xFFFF0000u;                              \
  float _r1 = (V)-__uint_as_float(U1);                                         \
  unsigned U2 = __float_as_uint(_r1) & 0xFFFF0000u;                            \
  float _r2 = _r1 - __uint_as_float(U2);                                       \
  unsigned U3 = __float_as_uint(_r2) & 0xFFFF0000u;

#define H1PL 8388608  // h1s plane stride in shorts: 32b x 128 x 128 x 16

// ---------------- Kernel A+setup: conv1 fused with weight-fold -----------------
// Blocks [0,2048): enc1 (r14 pre-split output, r12 XCD-slab mapping).
// Blocks [2048,2385): weight-fold (independent work) — r18: saves a dispatch.
__global__ __launch_bounds__(256) void k_enc1f(const float* __restrict__ x,
                                               const float* __restrict__ e1w,
                                               const float* __restrict__ e1b,
                                               unsigned short* __restrict__ h1s,
                                               const float* __restrict__ e2w,
                                               const float* __restrict__ d1w,
                                               const float* __restrict__ d2w,
                                               const float* __restrict__ cb,
                                               float* __restrict__ fwd2,
                                               unsigned short* __restrict__ cbs,
                                               float* __restrict__ csqg,
                                               unsigned short* __restrict__ wfrag,
                                               unsigned short* __restrict__ wfd1,
                                               float* __restrict__ lossout) {
  int n = blockIdx.x;
  if (n >= 2048) {
    // ---------------- fold branch ----------------
    int i = (n - 2048) * 256 + threadIdx.x;
    if (i == 0) lossout[0] = 0.f;  // k_vq accumulates atomically
    if (i < 256) {
      int j = i;
      int pt = j & 15, ic = j >> 4;
      int a = pt >> 3, b2 = (pt >> 2) & 1, dy = (pt >> 1) & 1, dx = pt & 1;
      const float* wsrc = d2w + ic * 9;
      float s = 0.f;
      for (int ky = 0; ky < 3; ++ky) {
        int rm = (a == 0) ? (ky == 0 ? 0 : 1) : (ky == 2 ? 1 : 0);
        if (rm != dy) continue;
        for (int kx = 0; kx < 3; ++kx) {
          int cm = (b2 == 0) ? (kx == 0 ? 0 : 1) : (kx == 2 ? 1 : 0);
          if (cm == dx) s += wsrc[ky * 3 + kx];
        }
      }
      fwd2[j] = s;
    } else if (i < 16640) {
      int j = i - 256;  // [0, 16384): code = j>>5, ch = j&31
      float v = cb[j];
      SPLIT3(v, u1, u2, u3)
      cbs[j] = (unsigned short)(u1 >> 16);
      cbs[16384 + j] = (unsigned short)(u2 >> 16);
      cbs[32768 + j] = (unsigned short)(u3 >> 16);
    } else if (i < 17152) {
      int c = i - 16640;
      const float* row = cb + (size_t)c * 32;
      float s = 0.f;
#pragma unroll
      for (int d = 0; d < 32; ++d) s = fmaf(row[d], row[d], s);
      csqg[c] = s;
    } else if (i < 30976) {
      int j = i - 17152;  // [0, 13824)
      int p = j / 4608, rem = j - p * 4608;
      int t = rem >> 9, l2 = (rem >> 3) & 63, jj = rem & 7;
      float v = e2w[((l2 & 31) * 16 + ((l2 >> 5) * 8 + jj)) * 9 + t];
      SPLIT3(v, u1, u2, u3)
      unsigned short r = (p == 0)   ? (unsigned short)(u1 >> 16)
                         : (p == 1) ? (unsigned short)(u2 >> 16)
                                    : (unsigned short)(u3 >> 16);
      wfrag[j] = r;
    } else if (i < 86272) {
      int j = i - 30976;  // [0, 55296)
      int slot = j >> 9, l2 = (j >> 3) & 63, jj = j & 7;
      int cx = slot / 36, rem = slot % 36;
      int r3 = rem / 12, rem2 = rem % 12;
      int kh = rem2 / 6, rem3 = rem2 % 6;
      int pp = rem3 / 3, part = rem3 % 3;
      int c = l2 & 31, hi = l2 >> 5;
      int oc = c & 15, b2 = c >> 4;
      int ic = kh * 16 + hi * 8 + jj;
      int dy = r3 - pp, dx = cx - b2;
      float s = 0.f;
      if ((unsigned)dy < 2u && (unsigned)dx < 2u) {
        const float* wsrc = d1w + (oc * 32 + ic) * 9;
        for (int ky = 0; ky < 3; ++ky) {
          int rm = (pp == 0) ? (ky == 0 ? 0 : 1) : (ky == 2 ? 1 : 0);
          if (rm != dy) continue;
          for (int kx = 0; kx < 3; ++kx) {
            int cm = (b2 == 0) ? (kx == 0 ? 0 : 1) : (kx == 2 ? 1 : 0);
            if (cm == dx) s += wsrc[ky * 3 + kx];
          }
        }
      }
      SPLIT3(s, u1, u2, u3)
      unsigned short r = (part == 0)   ? (unsigned short)(u1 >> 16)
                         : (part == 1) ? (unsigned short)(u2 >> 16)
                                       : (unsigned short)(u3 >> 16);
      wfd1[j] = r;
    }
    return;
  }
  // ---------------- enc1 branch ----------------
  int ysl = n & 7, m = n >> 3;
  int b = m & 31, k = m >> 5;
  int yy = ysl * 16 + k * 2 + (threadIdx.x >> 7);
  int xx = threadIdx.x & 127;
  const float* xp = x + (size_t)b * 65536;
  int r0 = 2 * yy - 1, c0 = 2 * xx - 1;
  float in[4][4];
#pragma unroll
  for (int i = 0; i < 4; ++i) {
    int r = r0 + i;
    bool rv = (unsigned)r < 256u;
#pragma unroll
    for (int j = 0; j < 4; ++j) {
      int c = c0 + j;
      in[i][j] = (rv && (unsigned)c < 256u) ? xp[r * 256 + c] : 0.0f;
    }
  }
  short8 p1[2], p2[2], p3[2];
#pragma unroll
  for (int oc = 0; oc < 16; ++oc) {
    const float* wp = e1w + oc * 9;  // uniform -> s_load
    float s00 = 0.f, s01 = 0.f, s10 = 0.f, s11 = 0.f;
#pragma unroll
    for (int ky = 0; ky < 3; ++ky)
#pragma unroll
      for (int kx = 0; kx < 3; ++kx) {
        float wv = wp[ky * 3 + kx];
        s00 = fmaf(in[ky][kx], wv, s00);
        s01 = fmaf(in[ky][kx + 1], wv, s01);
        s10 = fmaf(in[ky + 1][kx], wv, s10);
        s11 = fmaf(in[ky + 1][kx + 1], wv, s11);
      }
    float mm = fmaxf(fmaxf(s00, s01), fmaxf(s10, s11)) + e1b[oc];
    float g = GELU(mm);
    SPLIT3(g, u1, u2, u3)
    p1[oc >> 3][oc & 7] = (short)(u1 >> 16);
    p2[oc >> 3][oc & 7] = (short)(u2 >> 16);
    p3[oc >> 3][oc & 7] = (short)(u3 >> 16);
  }
  unsigned short* op = h1s + (size_t)b * 262144 + ((size_t)yy * 128 + xx) * 16;
  *(short8*)(op) = p1[0];
  *(short8*)(op + 8) = p1[1];
  *(short8*)(op + H1PL) = p2[0];
  *(short8*)(op + H1PL + 8) = p2[1];
  *(short8*)(op + 2 * H1PL) = p3[0];
  *(short8*)(op + 2 * H1PL + 8) = p3[1];
}

// ---------------- Kernel B: conv2 (16->32) + maxpool2 via split MFMA -----------
// (r14: pure 16B-copy staging from pre-split h1s; r12 XCD-matched grid.)
__global__ __launch_bounds__(256) void k_enc2(const unsigned short* __restrict__ h1s,
                                              const unsigned short* __restrict__ wfrag,
                                              const float* __restrict__ bias,
                                              float* __restrict__ h2) {
  __shared__ __align__(16) unsigned short sA[3 * 2 * 10 * 34 * 8];  // 32640 B
  const int PP = 2 * 10 * 34 * 8;
  int tid = threadIdx.x;
  int n = blockIdx.x;
  int xcd = n & 7, m = n >> 3;
  int ty = xcd * 2 + (m & 1);
  int q0 = m >> 1;
  int b = q0 >> 2, xt = q0 & 3;
  int X0 = xt * 32, Y0 = ty * 8;
  const unsigned short* ip = h1s + (size_t)b * 262144;
  for (int g = tid; g < 680; g += 256) {  // pos(340) x ich(2) granule-groups
    int pos = g >> 1, ich = g & 1;
    int yy = pos / 34, xx = pos - yy * 34;
    int y = Y0 - 1 + yy, xg = X0 - 1 + xx;
    short8 v1 = {0, 0, 0, 0, 0, 0, 0, 0};
    short8 v2 = {0, 0, 0, 0, 0, 0, 0, 0};
    short8 v3 = {0, 0, 0, 0, 0, 0, 0, 0};
    if ((unsigned)y < 128u && (unsigned)xg < 128u) {
      const unsigned short* sp = ip + ((size_t)y * 128 + xg) * 16 + ich * 8;
      v1 = *(const short8*)(sp);
      v2 = *(const short8*)(sp + H1PL);
      v3 = *(const short8*)(sp + 2 * H1PL);
    }
    int si = ((ich * 10 + yy) * 34 + xx) * 8;
    *(short8*)(sA + si) = v1;
    *(short8*)(sA + PP + si) = v2;
    *(short8*)(sA + 2 * PP + si) = v3;
  }
  __syncthreads();

  int l = tid & 63, w = tid >> 6;
  int xl = l & 31, ich = l >> 5;
  f32x16 acc0[2], acc1[2];
#pragma unroll
  for (int s = 0; s < 2; ++s)
#pragma unroll
    for (int r = 0; r < 16; ++r) { acc0[s][r] = 0.f; acc1[s][r] = 0.f; }

#pragma unroll
  for (int t = 0; t < 9; ++t) {
    int dy = t / 3, dx = t % 3;
    int s = t & 1;
    const unsigned short* wb = wfrag + t * 512 + l * 8;
    short8 bf1 = *(const short8*)(wb);
    short8 bf2 = *(const short8*)(wb + 4608);
    short8 bf3 = *(const short8*)(wb + 9216);
    int g0 = ((ich * 10) + (2 * w + dy)) * 34 + xl + dx;
    const unsigned short* a0p = sA + g0 * 8;
    short8 a01 = *(const short8*)(a0p);
    short8 a02 = *(const short8*)(a0p + PP);
    short8 a03 = *(const short8*)(a0p + 2 * PP);
    const unsigned short* a1p = a0p + 34 * 8;
    short8 a11 = *(const short8*)(a1p);
    short8 a12 = *(const short8*)(a1p + PP);
    short8 a13 = *(const short8*)(a1p + 2 * PP);
    acc0[s] = MFMA32(a01, bf1, acc0[s], 0, 0, 0);
    acc0[s] = MFMA32(a01, bf2, acc0[s], 0, 0, 0);
    acc0[s] = MFMA32(a02, bf1, acc0[s], 0, 0, 0);
    acc0[s] = MFMA32(a02, bf2, acc0[s], 0, 0, 0);
    acc0[s] = MFMA32(a01, bf3, acc0[s], 0, 0, 0);
    acc0[s] = MFMA32(a03, bf1, acc0[s], 0, 0, 0);
    acc1[s] = MFMA32(a11, bf1, acc1[s], 0, 0, 0);
    acc1[s] = MFMA32(a11, bf2, acc1[s], 0, 0, 0);
    acc1[s] = MFMA32(a12, bf1, acc1[s], 0, 0, 0);
    acc1[s] = MFMA32(a12, bf2, acc1[s], 0, 0, 0);
    acc1[s] = MFMA32(a11, bf3, acc1[s], 0, 0, 0);
    acc1[s] = MFMA32(a13, bf1, acc1[s], 0, 0, 0);
  }

  float bv = bias[l & 31];
  int ypool = (Y0 >> 1) + w;
  float* op = h2 + (size_t)b * 131072 + (size_t)(l & 31) * 4096 + ypool * 64 + (X0 >> 1);
#pragma unroll
  for (int k = 0; k < 8; ++k) {
    float e0 = (acc0[0][2 * k] + acc0[1][2 * k]);
    float o0 = (acc0[0][2 * k + 1] + acc0[1][2 * k + 1]);
    float e1 = (acc1[0][2 * k] + acc1[1][2 * k]);
    float o1 = (acc1[0][2 * k + 1] + acc1[1][2 * k + 1]);
    float mm = fmaxf(fmaxf(e0, o0), fmaxf(e1, o1)) + bv;
    int row = ((2 * k) & 3) + 8 * ((2 * k) >> 2) + 4 * ich;
    op[row >> 1] = mm;
  }
}

// ---------------- Kernel C: VQ via exact-split bf16 MFMA (v5) ------------------
// r19: 4-deep prefetch rotation (A,B,C,D). The r17 ping-pong gave only ~1
// COMPUTE (~150cyc) of cover per B-group vs ~200-400cyc L2 latency; distance-4
// gives 3 COMPUTEs (~450cyc). +48 VGPR (~190 total), safe under (256,2).
__global__ __launch_bounds__(256, 2) void k_vq(const float* __restrict__ h2,
                                               const unsigned short* __restrict__ cbs,
                                               const float* __restrict__ csqg,
                                               float* __restrict__ idxout,
                                               float* __restrict__ lossout) {
  __shared__ float sFsq[256];
  __shared__ float sBd[256];
  __shared__ int sBi[256];
  __shared__ float sred[4];
  int tid = threadIdx.x;
  int blk = blockIdx.x;
  int t0 = blk * 256;  // 16 blocks/batch: no batch straddle
  size_t abase = (size_t)(t0 >> 12) * 131072 + (t0 & 4095);

  int l = tid & 63, w = tid >> 6;
  int cl = l & 15, k0 = (l >> 4) * 8;

  // ---- direct staging: 4 tq x 8 ch per lane, split in-reg ----
  short8 af1[4], af2[4], af3[4];
  float fsq[4];
#pragma unroll
  for (int tq = 0; tq < 4; ++tq) {
    const float* src = h2 + abase + w * 64 + tq * 16 + cl;
    float fs = 0.f;
#pragma unroll
    for (int e = 0; e < 8; ++e) {
      float v = src[(size_t)(k0 + e) * 4096];
      fs = fmaf(v, v, fs);
      SPLIT3(v, u1, u2, u3)
      af1[tq][e] = (short)(u1 >> 16);
      af2[tq][e] = (short)(u2 >> 16);
      af3[tq][e] = (short)(u3 >> 16);
    }
    fsq[tq] = fs;
  }
#pragma unroll
  for (int tq = 0; tq < 4; ++tq) {  // total over the 4 k-groups of each token
    fsq[tq] += __shfl_xor(fsq[tq], 16, 64);
    fsq[tq] += __shfl_xor(fsq[tq], 32, 64);
  }
  if (l < 16) {
#pragma unroll
    for (int tq = 0; tq < 4; ++tq) sFsq[w * 64 + tq * 16 + l] = fsq[tq];
  }

  float bd[4][4];
  int bi[4][4];
#pragma unroll
  for (int a = 0; a < 4; ++a)
#pragma unroll
    for (int b = 0; b < 4; ++b) { bd[a][b] = 3.4e38f; bi[a][b] = 0; }

#define LOADB(S, CT)                                                           \
  {                                                                            \
    int col = (CT)*16 + cl;                                                    \
    b1##S = *(const short8*)(cbs + (0 * 512 + col) * 32 + k0);                 \
    b2##S = *(const short8*)(cbs + (1 * 512 + col) * 32 + k0);                 \
    b3##S = *(const short8*)(cbs + (2 * 512 + col) * 32 + k0);                 \
    cq##S = csqg[col];                                                         \
  }
#define COMPUTE(S, CT)                                                         \
  {                                                                            \
    _Pragma("unroll") for (int tq = 0; tq < 4; ++tq) {                         \
      f32x4 acc = {0.f, 0.f, 0.f, 0.f};                                        \
      acc = MFMA16(af1[tq], b1##S, acc, 0, 0, 0);                              \
      acc = MFMA16(af1[tq], b2##S, acc, 0, 0, 0);                              \
      acc = MFMA16(af2[tq], b1##S, acc, 0, 0, 0);                              \
      acc = MFMA16(af2[tq], b2##S, acc, 0, 0, 0);                              \
      acc = MFMA16(af1[tq], b3##S, acc, 0, 0, 0);                              \
      acc = MFMA16(af3[tq], b1##S, acc, 0, 0, 0);                              \
      _Pragma("unroll") for (int i = 0; i < 4; ++i) {                          \
        float d = fmaf(-2.f, acc[i], cq##S);                                   \
        if (d < bd[tq][i]) { bd[tq][i] = d; bi[tq][i] = (CT)*16 + cl; }        \
      }                                                                        \
    }                                                                          \
  }

  short8 b1A, b2A, b3A, b1B, b2B, b3B, b1C, b2C, b3C, b1D, b2D, b3D;
  float cqA, cqB, cqC, cqD;
  LOADB(A, 0)
  LOADB(B, 1)
  LOADB(C, 2)
  LOADB(D, 3)
#pragma unroll 1
  for (int ct = 0; ct < 32; ct += 4) {
    COMPUTE(A, ct)
    LOADB(A, (ct + 4) & 31)  // distance-4 prefetch; wrap: in-bounds, unused
    COMPUTE(B, ct + 1)
    LOADB(B, (ct + 5) & 31)
    COMPUTE(C, ct + 2)
    LOADB(C, (ct + 6) & 31)
    COMPUTE(D, ct + 3)
    LOADB(D, (ct + 7) & 31)
  }
#undef LOADB
#undef COMPUTE

  // ---- cross-lane argmin over 16 code-slices (lexicographic) ----
#pragma unroll
  for (int tq = 0; tq < 4; ++tq)
#pragma unroll
    for (int i = 0; i < 4; ++i)
#pragma unroll
      for (int m = 1; m < 16; m <<= 1) {
        float od = __shfl_xor(bd[tq][i], m, 64);
        int ob = __shfl_xor(bi[tq][i], m, 64);
        if (od < bd[tq][i] || (od == bd[tq][i] && ob < bi[tq][i])) {
          bd[tq][i] = od;
          bi[tq][i] = ob;
        }
      }
  if (cl == 0) {
#pragma unroll
    for (int tq = 0; tq < 4; ++tq)
#pragma unroll
      for (int i = 0; i < 4; ++i) {
        int tokl = w * 64 + tq * 16 + (l >> 4) * 4 + i;
        sBi[tokl] = bi[tq][i];
        sBd[tokl] = bd[tq][i];
      }
  }
  __syncthreads();

  idxout[t0 + tid] = (float)sBi[tid];
  float loss = sBd[tid] + sFsq[tid];  // ||q-f||^2 = csq - 2 f.c + ||f||^2
#pragma unroll
  for (int off = 32; off > 0; off >>= 1) loss += __shfl_down(loss, off, 64);
  if (l == 0) sred[w] = loss;
  __syncthreads();
  if (tid == 0)
    atomicAdd(lossout, ((sred[0] + sred[1]) + (sred[2] + sred[3])) * (1.0f / 4194304.0f));
}

// ---------------- Kernel D: up2 + conv (32->16) + gelu via split MFMA ----------
// (r13-verified: gather-direct A, 1 q-row/wave, interleaved d1o.)
__global__ __launch_bounds__(256) void k_dec1(const float* __restrict__ idxf,
                                              const unsigned short* __restrict__ cbs,
                                              const unsigned short* __restrict__ wfd1,
                                              const float* __restrict__ bias,
                                              float* __restrict__ o) {
  __shared__ int sIdx[204];  // 6 halo rows x 34 cols
  int tid = threadIdx.x;
  int b = blockIdx.y;
  int qx0 = (blockIdx.x & 1) * 32, qy0 = (blockIdx.x >> 1) * 4;
  const float* ib = idxf + (size_t)b * 4096;
  if (tid < 204) {
    int yy = tid / 34, xx = tid % 34;
    int y = qy0 - 1 + yy, x = qx0 - 1 + xx;
    sIdx[tid] = ((unsigned)y < 64u && (unsigned)x < 64u) ? (int)ib[y * 64 + x] : -1;
  }
  __syncthreads();

  int l = tid & 63, w = tid >> 6;  // wave w -> output q-row qy0+w
  int xl = l & 31, hi = l >> 5;
  f32x16 acc[2];  // [p2 = output row phase]
#pragma unroll
  for (int p2 = 0; p2 < 2; ++p2)
#pragma unroll
    for (int r = 0; r < 16; ++r) acc[p2][r] = 0.f;

#pragma unroll
  for (int cx = 0; cx < 3; ++cx) {
#pragma unroll
    for (int kh = 0; kh < 2; ++kh) {
      short8 Bf[4][3];  // q=(ry,pq) packed: 0:(0,0) 1:(1,0) 2:(1,1) 3:(2,1)
#pragma unroll
      for (int q = 0; q < 4; ++q) {
        int r3 = (q == 0) ? 0 : (q == 3) ? 2 : 1;
        int pq = (q >= 2) ? 1 : 0;
#pragma unroll
        for (int pt = 0; pt < 3; ++pt) {
          int slot = cx * 36 + r3 * 12 + kh * 6 + pq * 3 + pt;
          Bf[q][pt] = *(const short8*)(wfd1 + (size_t)slot * 512 + l * 8);
        }
      }
#pragma unroll
      for (int ry = 0; ry < 3; ++ry) {
        int idx = sIdx[(w + ry) * 34 + xl + cx];
        short8 a1 = {0, 0, 0, 0, 0, 0, 0, 0};
        short8 a2 = {0, 0, 0, 0, 0, 0, 0, 0};
        short8 a3 = {0, 0, 0, 0, 0, 0, 0, 0};
        if (idx >= 0) {
          const unsigned short* ap = cbs + (size_t)idx * 32 + kh * 16 + hi * 8;
          a1 = *(const short8*)(ap);
          a2 = *(const short8*)(ap + 16384);
          a3 = *(const short8*)(ap + 32768);
        }
#pragma unroll
        for (int p2 = 0; p2 < 2; ++p2) {
          if ((ry == 0 && p2 == 1) || (ry == 2 && p2 == 0)) continue;
          int q = ry + p2;
          f32x16 t = acc[p2];
          t = MFMA32(a1, Bf[q][0], t, 0, 0, 0);
          t = MFMA32(a1, Bf[q][1], t, 0, 0, 0);
          t = MFMA32(a2, Bf[q][0], t, 0, 0, 0);
          t = MFMA32(a2, Bf[q][1], t, 0, 0, 0);
          t = MFMA32(a1, Bf[q][2], t, 0, 0, 0);
          t = MFMA32(a3, Bf[q][0], t, 0, 0, 0);
          acc[p2] = t;
        }
      }
    }
  }

  float bv = bias[l & 15];
  int b2 = (l >> 4) & 1;
  int oc = l & 15;
  int qy = qy0 + w;
  float* ob = o + (size_t)b * 262144;
#pragma unroll
  for (int p2 = 0; p2 < 2; ++p2) {
    int Y = 2 * qy + p2;
#pragma unroll
    for (int reg = 0; reg < 16; ++reg) {
      int rowval = (reg & 3) + 8 * (reg >> 2) + 4 * hi;
      int X = qx0 * 2 + 2 * rowval + b2;
      ob[((size_t)Y * 128 + X) * 16 + oc] = GELU(acc[p2][reg] + bv);
    }
  }
}

// ---------------- Kernel E: up2 + conv (16->1) + clip, phase-folded ------------
// (r13-verified: interleaved input, position-major LDS [pos][17].)
__device__ __forceinline__ void d2_loadi3(float (&dst)[3][3], const float* t) {
#pragma unroll
  for (int dy = 0; dy < 3; ++dy)
#pragma unroll
    for (int dx = 0; dx < 3; ++dx) dst[dy][dx] = t[(dy * 18 + dx) * 17];
}
__global__ __launch_bounds__(256) void k_dec2(const float* __restrict__ d1,
                                              const float* __restrict__ fwd2,
                                              const float* __restrict__ bias,
                                              float* __restrict__ out) {
  __shared__ float st[18 * 18 * 17];  // [row][col][ic16 + pad]
  int tid = threadIdx.x;
  int b = blockIdx.y;
  int R0 = (blockIdx.x >> 3) * 16, C0 = (blockIdx.x & 7) * 16;
  const float* ip = d1 + (size_t)b * 262144;
  for (int i = tid; i < 1296; i += 256) {  // 324 pos x 4 ic-quads
    int pos = i >> 2, q = i & 3;
    int rr = pos / 18, cc = pos % 18;
    int r = R0 - 1 + rr, c = C0 - 1 + cc;
    float4 v = {0.f, 0.f, 0.f, 0.f};
    if ((unsigned)r < 128u && (unsigned)c < 128u)
      v = *(const float4*)(ip + ((size_t)r * 128 + c) * 16 + q * 4);
    float* dp = st + (rr * 18 + cc) * 17 + q * 4;
    dp[0] = v.x; dp[1] = v.y; dp[2] = v.z; dp[3] = v.w;
  }
  __syncthreads();
  int lane = tid & 63, wid = tid >> 6;
  int qy = wid >> 1, qx = wid & 1;
  int ty = qy * 8 + (lane >> 3), tx = qx * 8 + (lane & 7);
  float acc[4] = {0.f, 0.f, 0.f, 0.f};
  const float* tb = st + (ty * 18 + tx) * 17;
  float i3A[3][3], i3B[3][3];
  d2_loadi3(i3A, tb);
#pragma unroll 1
  for (int ic = 0; ic < 16; ic += 2) {
    d2_loadi3(i3B, tb + (ic + 1));
    {
      const float* wp = fwd2 + ic * 16;  // scalar loads
#pragma unroll
      for (int p = 0; p < 4; ++p) {
        int a = p >> 1, b2 = p & 1;
#pragma unroll
        for (int tp = 0; tp < 4; ++tp) {
          int dy = tp >> 1, dx = tp & 1;
          acc[p] = fmaf(i3A[a + dy][b2 + dx], wp[p * 4 + tp], acc[p]);
        }
      }
    }
    d2_loadi3(i3A, tb + ((ic + 2) & 15));  // wrap: harmless re-read
    {
      const float* wp = fwd2 + (ic + 1) * 16;
#pragma unroll
      for (int p = 0; p < 4; ++p) {
        int a = p >> 1, b2 = p & 1;
#pragma unroll
        for (int tp = 0; tp < 4; ++tp) {
          int dy = tp >> 1, dx = tp & 1;
          acc[p] = fmaf(i3B[a + dy][b2 + dx], wp[p * 4 + tp], acc[p]);
        }
      }
    }
  }
  float bv = bias[0];
  int Y = 2 * (R0 + ty), X = 2 * (C0 + tx);
  float* op = out + (size_t)b * 65536 + Y * 256 + X;
  float2 r0v, r1v;
  r0v.x = fminf(1.0f, fmaxf(-1.0f, acc[0] + bv));
  r0v.y = fminf(1.0f, fmaxf(-1.0f, acc[1] + bv));
  r1v.x = fminf(1.0f, fmaxf(-1.0f, acc[2] + bv));
  r1v.y = fminf(1.0f, fmaxf(-1.0f, acc[3] + bv));
  *(float2*)op = r0v;
  *(float2*)(op + 256) = r1v;
}

extern "C" void kernel_launch(void* const* d_in, const int* in_sizes, int n_in,
                              void* d_out, int out_size, void* d_ws, size_t ws_size,
                              hipStream_t stream) {
  const float* x   = (const float*)d_in[0];
  const float* e1w = (const float*)d_in[1];
  const float* e1b = (const float*)d_in[2];
  const float* e2w = (const float*)d_in[3];
  const float* e2b = (const float*)d_in[4];
  const float* cb  = (const float*)d_in[5];
  const float* d1w = (const float*)d_in[6];
  const float* d1b = (const float*)d_in[7];
  const float* d2w = (const float*)d_in[8];
  const float* d2b = (const float*)d_in[9];

  float* out = (float*)d_out;
  float* y       = out;                       // [32,1,256,256] = 2097152
  float* idxout  = out + 2097152;             // [32,64,64]     = 131072 (as float)
  float* lossout = out + 2097152 + 131072;    // scalar

  // Workspace layout:
  //  h1s: 3 bf16 planes, 3 x 8388608 shorts = 12582912 floats  [0, 12582912)
  //  h2 : fp32 [32][32][64][64]                                [12582912, 16777216)
  //  fwd2: 256 floats                                          [16777216, ...)
  //  d1o: fp32 [32][128][128][16], reuses h1s region (dead after enc2)
  float* ws = (float*)d_ws;
  unsigned short* h1s = (unsigned short*)ws;
  float* h2      = ws + 12582912;
  float* fwd2    = ws + 16777216;
  float* d1o     = ws;  // 8388608 floats, fits in h1s region

  // Scratch in the y-region of out (written by the fold branch, consumed before
  // k_dec2 overwrites all of y): cbs 24576f, csqg 512f, wfrag 6912f, wfd1 27648f.
  unsigned short* cbs = (unsigned short*)out;              // 49152 bf16
  float* csqg = out + 24576;                               // 512
  unsigned short* wfrag = (unsigned short*)(out + 25088);  // 13824 bf16
  unsigned short* wfd1 = (unsigned short*)(out + 32000);   // 55296 bf16

  k_enc1f<<<dim3(2385), 256, 0, stream>>>(x, e1w, e1b, h1s, e2w, d1w, d2w, cb,
                                          fwd2, cbs, csqg, wfrag, wfd1, lossout);
  k_enc2<<<dim3(2048), 256, 0, stream>>>(h1s, wfrag, e2b, h2);
  k_vq<<<dim3(512), 256, 0, stream>>>(h2, cbs, csqg, idxout, lossout);
  k_dec1<<<dim3(32, 32), 256, 0, stream>>>(idxout, cbs, wfd1, d1b, d1o);
  k_dec2<<<dim3(64, 32), 256, 0, stream>>>(d1o, fwd2, d2b, y);
}